// Round 20
// baseline (61.163 us; speedup 1.0000x reference)
//
#include <hip/hip_runtime.h>

#define NB 4
#define NCI 64
#define NCO 64
#define PLANE 65536

// workspace offsets (floats): two partial-xs buffers (re,im each), then o1/o2
#define OF_XS0_RE 0
#define OF_XS0_IM (OF_XS0_RE + PLANE)
#define OF_XS1_RE (2*PLANE)
#define OF_XS1_IM (3*PLANE)
#define OF_O1_RE (4*PLANE)
#define OF_O1_IM (OF_O1_RE + PLANE)
#define OF_O2_RE (OF_O1_IM + PLANE)
#define OF_O2_IM (OF_O2_RE + PLANE)

// stage1 LDS plane layout (128-row planes, pad to 132; xo at +8 stagger)
#define PL2 132
#define XE2(w) ((w)*PL2)
#define XO2(w) (16*PL2 + 8 + (w)*PL2)

#define TPF 6.2831853071795864769f

// Fused stage 1+2, HALF-IMAGE per block: grid 512 = (img, half), 512 threads,
// 2 independent blocks/CU (the R18 1-block/CU version had no co-resident block
// to hide its ~10 barriers). Same rolled-dbuf chunk loop; partial h-DFT over
// the block's 128 rows -> xs0/xs1; k3 sums the two partials.
__global__ __launch_bounds__(512, 4) void k12_dft(const float* __restrict__ x,
                                                  float* __restrict__ ws) {
  __shared__ float bufA[4232], bufB[4232];
  __shared__ float cst[256], snt[256];
  __shared__ float2 s2[512];
  const int t = threadIdx.x;
  const int img  = blockIdx.x >> 1;
  const int half = blockIdx.x & 1;
  const int r0   = half << 7;          // 0 or 128

  if (t < 256) {
    float sv_, cv_;
    sincosf(TPF * (float)t * (1.0f/256.0f), &sv_, &cv_);
    cst[t] = cv_;  snt[t] = sv_;
  }

  const int sl = t & 3, row = t >> 2;            // staging: row 0..127
  const int wq = t & 3, p = (t >> 2) & 1;        // compute map
  const int kg = (t >> 3) & 1, tr = t >> 4;      // tr 0..31 (row-quads)
  int kyv[4];
#pragma unroll
  for (int j = 0; j < 4; ++j) kyv[j] = p + 8*kg + 2*j;

  const float* xb = x + (size_t)img * 65536 + (size_t)r0 * 256;

  // prologue: issue chunk-0 loads
  float4 lo = *(const float4*)(xb + row*256 + sl*4);
  float4 hi = *(const float4*)(xb + row*256 + 128 + sl*4);

  __syncthreads();                     // cst/snt ready

  float cd[4], sd[4];
#pragma unroll
  for (int j = 0; j < 4; ++j) { cd[j] = cst[kyv[j]]; sd[j] = snt[kyv[j]]; }

  float ar[4][4], ai[4][4];
#pragma unroll
  for (int j = 0; j < 4; ++j)
#pragma unroll
    for (int r = 0; r < 4; ++r) { ar[j][r] = 0.f; ai[j][r] = 0.f; }

  // stage chunk 0 into bufA
  bufA[XE2(sl*4+0) + row] = lo.x + hi.x;
  bufA[XE2(sl*4+1) + row] = lo.y + hi.y;
  bufA[XE2(sl*4+2) + row] = lo.z + hi.z;
  bufA[XE2(sl*4+3) + row] = lo.w + hi.w;
  bufA[XO2(sl*4+0) + row] = lo.x - hi.x;
  bufA[XO2(sl*4+1) + row] = lo.y - hi.y;
  bufA[XO2(sl*4+2) + row] = lo.z - hi.z;
  bufA[XO2(sl*4+3) + row] = lo.w - hi.w;
  __syncthreads();                     // chunk 0 staged

  const int pofs = p ? (16*PL2 + 8) : 0;

  for (int c = 0; c < 8; ++c) {        // ROLLED — do not unroll (spill)
    float* cur = (c & 1) ? bufB : bufA;
    float* nxt = (c & 1) ? bufA : bufB;
    if (c < 7) {                       // issue next-chunk loads early
      const int w0n = (c+1) * 16;
      lo = *(const float4*)(xb + row*256 + w0n + sl*4);
      hi = *(const float4*)(xb + row*256 + w0n + 128 + sl*4);
    }
    float cc[4], sv[4];
#pragma unroll
    for (int j = 0; j < 4; ++j) {
      const int m = (kyv[j] * (c*16 + wq*4)) & 255;
      cc[j] = cst[m];
      sv[j] = snt[m];
    }
    const float* rp = cur + pofs;
#pragma unroll
    for (int i = 0; i < 4; ++i) {
      const int wl = wq*4 + i;
      const float4 xs4 = *(const float4*)&rp[wl*PL2 + tr*4];
#pragma unroll
      for (int j = 0; j < 4; ++j) {
        ar[j][0] += xs4.x * cc[j];  ai[j][0] -= xs4.x * sv[j];
        ar[j][1] += xs4.y * cc[j];  ai[j][1] -= xs4.y * sv[j];
        ar[j][2] += xs4.z * cc[j];  ai[j][2] -= xs4.z * sv[j];
        ar[j][3] += xs4.w * cc[j];  ai[j][3] -= xs4.w * sv[j];
        const float nc = cc[j]*cd[j] - sv[j]*sd[j];
        const float ns = sv[j]*cd[j] + cc[j]*sd[j];
        cc[j] = nc; sv[j] = ns;
      }
    }
    if (c < 7) {                       // stage chunk c+1 into nxt
      nxt[XE2(sl*4+0) + row] = lo.x + hi.x;
      nxt[XE2(sl*4+1) + row] = lo.y + hi.y;
      nxt[XE2(sl*4+2) + row] = lo.z + hi.z;
      nxt[XE2(sl*4+3) + row] = lo.w + hi.w;
      nxt[XO2(sl*4+0) + row] = lo.x - hi.x;
      nxt[XO2(sl*4+1) + row] = lo.y - hi.y;
      nxt[XO2(sl*4+2) + row] = lo.z - hi.z;
      nxt[XO2(sl*4+3) + row] = lo.w - hi.w;
    }
    __syncthreads();                   // ONE barrier per chunk
  }

#pragma unroll
  for (int j = 0; j < 4; ++j)
#pragma unroll
    for (int r = 0; r < 4; ++r) {
      ar[j][r] += __shfl_xor(ar[j][r], 1);
      ar[j][r] += __shfl_xor(ar[j][r], 2);
      ai[j][r] += __shfl_xor(ai[j][r], 1);
      ai[j][r] += __shfl_xor(ai[j][r], 2);
    }
  if (wq == 0) {                       // Xw planes (128 rows) into bufA
#pragma unroll
    for (int j = 0; j < 4; ++j) {
      const int ky = kyv[j];
      float4 sr; sr.x = ar[j][0]; sr.y = ar[j][1]; sr.z = ar[j][2]; sr.w = ar[j][3];
      float4 si; si.x = ai[j][0]; si.y = ai[j][1]; si.z = ai[j][2]; si.w = ai[j][3];
      *(float4*)&bufA[XE2(ky) + tr*4] = sr;
      *(float4*)&bufA[XO2(ky) + tr*4] = si;
    }
  }
  __syncthreads();

  // phase B: partial h-DFT over this block's 128 rows (global h = r0 + local)
  const int ky2 = t & 15, kx = (t >> 4) & 15, hh = t >> 8;   // hh 0..1
  const float cdk = cst[kx], sdk = snt[kx];
  const int m0 = (kx * (r0 + hh*64)) & 255;
  float cR = cst[m0], sR = snt[m0];
  float arr = 0.f, aii = 0.f;
  const int be = XE2(ky2) + hh*64;
  const int bo = XO2(ky2) + hh*64;
#pragma unroll 4
  for (int hq = 0; hq < 16; ++hq) {
    const float4 xr = *(const float4*)&bufA[be + hq*4];
    const float4 xi = *(const float4*)&bufA[bo + hq*4];
    {
      arr += xr.x*cR + xi.x*sR;  aii += xi.x*cR - xr.x*sR;
      const float nc = cR*cdk - sR*sdk, ns = sR*cdk + cR*sdk; cR = nc; sR = ns;
    }
    {
      arr += xr.y*cR + xi.y*sR;  aii += xi.y*cR - xr.y*sR;
      const float nc = cR*cdk - sR*sdk, ns = sR*cdk + cR*sdk; cR = nc; sR = ns;
    }
    {
      arr += xr.z*cR + xi.z*sR;  aii += xi.z*cR - xr.z*sR;
      const float nc = cR*cdk - sR*sdk, ns = sR*cdk + cR*sdk; cR = nc; sR = ns;
    }
    {
      arr += xr.w*cR + xi.w*sR;  aii += xi.w*cR - xr.w*sR;
      const float nc = cR*cdk - sR*sdk, ns = sR*cdk + cR*sdk; cR = nc; sR = ns;
    }
  }
  s2[t].x = arr; s2[t].y = aii;
  __syncthreads();
  if (t < 256) {
    const float xre = s2[t].x + s2[t+256].x;
    const float xim = s2[t].y + s2[t+256].y;
    const int base = half ? OF_XS1_RE : OF_XS0_RE;
    ws[base + img*256 + t]         = xre;
    ws[base + PLANE + img*256 + t] = xim;
  }
}

// Stage 3: o1/o2[b,o,m] = sum_i xs[b,i,m] * (wr + i wi)[i,o,m]
// xs = xs0 + xs1 (partials from the two half-image blocks; L2-resident)
__global__ __launch_bounds__(256) void k3_mix(const float* __restrict__ w1r,
    const float* __restrict__ w1i, const float* __restrict__ w2r,
    const float* __restrict__ w2i, float* __restrict__ ws) {
  const int o  = blockIdx.x;     // 0..63
  const int mc = blockIdx.y;     // 0..3
  const int t  = threadIdx.x;    // 256
  const int b  = t >> 6;
  const int m  = (mc << 6) + (t & 63);
  float a1r=0.f, a1i=0.f, a2r=0.f, a2i=0.f;
#pragma unroll 4
  for (int i = 0; i < NCI; ++i) {
    const int idx = ((b*NCI + i) << 8) + m;
    const float xr = ws[OF_XS0_RE + idx] + ws[OF_XS1_RE + idx];
    const float xi = ws[OF_XS0_IM + idx] + ws[OF_XS1_IM + idx];
    const int wi = ((i*NCO + o) << 8) + m;
    const float p = w1r[wi], q = w1i[wi], u = w2r[wi], v = w2i[wi];
    a1r += xr*p - xi*q;
    a1i += xr*q + xi*p;
    a2r += xr*u - xi*v;
    a2i += xr*v + xi*u;
  }
  const int oi = ((b*NCO + o) << 8) + m;
  ws[OF_O1_RE + oi] = a1r;
  ws[OF_O1_IM + oi] = a1i;
  ws[OF_O2_RE + oi] = a2r;
  ws[OF_O2_IM + oi] = a2i;
}

// Fused stage 4+5 (R19-verbatim).
__global__ __launch_bounds__(256) void k45_idft(const float* __restrict__ ws,
                                                float* __restrict__ out) {
  __shared__ __align__(16) float o1r[256], o1i[256], o2r[256], o2i[256];
  __shared__ float cst[256], snt[256];
  __shared__ __align__(16) float Sr[64][20], Si[64][20];
  const int t  = threadIdx.x;
  const int bo = blockIdx.x >> 2;
  const int hc = blockIdx.x & 3;

  o1r[t] = ws[OF_O1_RE + bo*256 + t];
  o1i[t] = ws[OF_O1_IM + bo*256 + t];
  o2r[t] = ws[OF_O2_RE + bo*256 + t];
  o2i[t] = ws[OF_O2_IM + bo*256 + t];
  {
    float sv_, cv_;
    sincosf(TPF * (float)t * (1.0f/256.0f), &sv_, &cv_);
    cst[t] = cv_;  snt[t] = sv_;
  }
  __syncthreads();

  const int wl = t & 31;
  float c[15], s[15], c2[15], s2[15];
#pragma unroll
  for (int k = 0; k < 15; ++k) {
    const int mi = ((k+1) * wl) & 255;
    c[k] = cst[mi];
    s[k] = snt[mi];
  }
  {
    const float R = 0.70710678118654752f;
#pragma unroll
    for (int k = 0; k < 15; ++k) {
      const int r8 = (k + 1) & 7;
      switch (r8) {
        case 0: c2[k] =  c[k];            s2[k] =  s[k];            break;
        case 1: c2[k] = (c[k]-s[k])*R;    s2[k] = (s[k]+c[k])*R;    break;
        case 2: c2[k] = -s[k];            s2[k] =  c[k];            break;
        case 3: c2[k] = -(c[k]+s[k])*R;   s2[k] = (c[k]-s[k])*R;    break;
        case 4: c2[k] = -c[k];            s2[k] = -s[k];            break;
        case 5: c2[k] = (s[k]-c[k])*R;    s2[k] = -(c[k]+s[k])*R;   break;
        case 6: c2[k] =  s[k];            s2[k] = -c[k];            break;
        default:c2[k] = (c[k]+s[k])*R;    s2[k] = (s[k]-c[k])*R;    break;
      }
    }
  }

  // ---- phase A ----
  {
    const int hl = t >> 2, kq = t & 3;
    const int h  = hc*64 + hl;
    const float chh = cst[h], shh = snt[h];
    float c1 = 1.f, s1 = 0.f;
    const int m2i = (240 * h) & 255;
    float cB = cst[m2i], sB = snt[m2i];
    float4 sr = {0.f,0.f,0.f,0.f}, si = {0.f,0.f,0.f,0.f};
    for (int j = 0; j < 16; ++j) {
      const float4 r1 = *(const float4*)&o1r[j*16 + kq*4];
      const float4 i1 = *(const float4*)&o1i[j*16 + kq*4];
      const float4 r2 = *(const float4*)&o2r[j*16 + kq*4];
      const float4 i2 = *(const float4*)&o2i[j*16 + kq*4];
      sr.x += r1.x*c1 - i1.x*s1 + r2.x*cB - i2.x*sB;
      si.x += r1.x*s1 + i1.x*c1 + r2.x*sB + i2.x*cB;
      sr.y += r1.y*c1 - i1.y*s1 + r2.y*cB - i2.y*sB;
      si.y += r1.y*s1 + i1.y*c1 + r2.y*sB + i2.y*cB;
      sr.z += r1.z*c1 - i1.z*s1 + r2.z*cB - i2.z*sB;
      si.z += r1.z*s1 + i1.z*c1 + r2.z*sB + i2.z*cB;
      sr.w += r1.w*c1 - i1.w*s1 + r2.w*cB - i2.w*sB;
      si.w += r1.w*s1 + i1.w*c1 + r2.w*sB + i2.w*cB;
      const float n1c = c1*chh - s1*shh, n1s = s1*chh + c1*shh;
      const float n2c = cB*chh - sB*shh, n2s = sB*chh + cB*shh;
      c1 = n1c; s1 = n1s; cB = n2c; sB = n2s;
    }
    *(float4*)&Sr[hl][kq*4] = sr;
    *(float4*)&Si[hl][kq*4] = si;
  }
  __syncthreads();

  // ---- phase B: row-paired, radix-4 butterfly x2 trig sets ----
  const int half = (t >> 5) & 1;
  const int wv = t >> 6;
  const float scale = 2.0f / 65536.0f;
  const size_t tilebase = ((size_t)bo*256 + hc*64) * 256;
#pragma unroll 2
  for (int pr = 0; pr < 8; ++pr) {
    const int hl = wv*16 + pr*2 + half;
    const float4 a0 = *(const float4*)&Sr[hl][0];
    const float4 a1 = *(const float4*)&Sr[hl][4];
    const float4 a2 = *(const float4*)&Sr[hl][8];
    const float4 a3 = *(const float4*)&Sr[hl][12];
    const float4 b0 = *(const float4*)&Si[hl][0];
    const float4 b1 = *(const float4*)&Si[hl][4];
    const float4 b2 = *(const float4*)&Si[hl][8];
    const float4 b3 = *(const float4*)&Si[hl][12];
    const float re[16] = {a0.x,a0.y,a0.z,a0.w, a1.x,a1.y,a1.z,a1.w,
                          a2.x,a2.y,a2.z,a2.w, a3.x,a3.y,a3.z,a3.w};
    const float im[16] = {b0.x,b0.y,b0.z,b0.w, b1.x,b1.y,b1.z,b1.w,
                          b2.x,b2.y,b2.z,b2.w, b3.x,b3.y,b3.z,b3.w};
    const size_t ob = tilebase + (size_t)hl*256;

#pragma unroll
    for (int g = 0; g < 2; ++g) {
      const float* cc = g ? c2 : c;
      const float* ss = g ? s2 : s;
      float PA = 0.5f * re[0];
      float PB = 0.f, PC = 0.f, PD = 0.f, QB = 0.f, QD = 0.f;
#pragma unroll
      for (int k = 0; k < 15; ++k) {
        const int ky = k + 1;
        const float R = re[ky], I = im[ky];
        const int cls = ky & 3;
        if (cls == 0)      PA += R*cc[k] - I*ss[k];
        else if (cls == 1) { PB += R*cc[k] - I*ss[k];  QB += R*ss[k] + I*cc[k]; }
        else if (cls == 2) PC += R*cc[k] - I*ss[k];
        else               { PD += R*cc[k] - I*ss[k];  QD += R*ss[k] + I*cc[k]; }
      }
      const float T1 = PA + PC, T2 = PB + PD;
      const float T3 = PA - PC, T4 = QB - QD;
      const int cb = wl + g*32;
      out[ob + cb]       = (T1 + T2) * scale;
      out[ob + cb + 64]  = (T3 - T4) * scale;
      out[ob + cb + 128] = (T1 - T2) * scale;
      out[ob + cb + 192] = (T3 + T4) * scale;
    }
  }
}

extern "C" void kernel_launch(void* const* d_in, const int* in_sizes, int n_in,
                              void* d_out, int out_size, void* d_ws, size_t ws_size,
                              hipStream_t stream) {
  const float* x   = (const float*)d_in[0];
  const float* w1r = (const float*)d_in[1];
  const float* w1i = (const float*)d_in[2];
  const float* w2r = (const float*)d_in[3];
  const float* w2i = (const float*)d_in[4];
  float* out = (float*)d_out;
  float* ws  = (float*)d_ws;

  hipLaunchKernelGGL(k12_dft,  dim3(512),   dim3(512), 0, stream, x, ws);
  hipLaunchKernelGGL(k3_mix,   dim3(64, 4), dim3(256), 0, stream, w1r, w1i, w2r, w2i, ws);
  hipLaunchKernelGGL(k45_idft, dim3(1024),  dim3(256), 0, stream, ws, out);
}

// Round 21
// 57.626 us; speedup vs baseline: 1.0614x; 1.0614x over previous
//
#include <hip/hip_runtime.h>

#define NB 4
#define NCI 64
#define NCO 64
#define PLANE 65536

// workspace offsets (in floats) — trig tables computed in-kernel
#define OF_XS_RE 0
#define OF_XS_IM (OF_XS_RE + PLANE)
#define OF_O1_RE (OF_XS_IM + PLANE)
#define OF_O1_IM (OF_O1_RE + PLANE)
#define OF_O2_RE (OF_O1_IM + PLANE)
#define OF_O2_IM (OF_O2_RE + PLANE)

// stage1 LDS plane layout (per buffer)
#define XEOFF(w) ((w)*260)
#define XOOFF(w) (16*260 + 8 + (w)*260)

#define TPF 6.2831853071795864769f

// Fused stage 1+2 (R19-verbatim, best measured: 1024 threads, grid 256,
// rolled dbuf chunk loop, launch_bounds(1024,4), in-kernel trig).
__global__ __launch_bounds__(1024, 4) void k12_dft(const float* __restrict__ x,
                                                   float* __restrict__ ws) {
  __shared__ float bufA[8336], bufB[8336];
  __shared__ float cst[256], snt[256];
  __shared__ float2 s2[1024];
  const int t = threadIdx.x;
  const int img = blockIdx.x;

  if (t < 256) {
    float sv_, cv_;
    sincosf(TPF * (float)t * (1.0f/256.0f), &sv_, &cv_);
    cst[t] = cv_;  snt[t] = sv_;
  }

  const int sl = t & 3, row = t >> 2;
  const int wq = t & 3, p = (t >> 2) & 1;
  const int kg = (t >> 3) & 1, tr = t >> 4;
  int kyv[4];
#pragma unroll
  for (int j = 0; j < 4; ++j) kyv[j] = p + 8*kg + 2*j;

  const float* xb = x + (size_t)img * 65536;

  float4 lo = *(const float4*)(xb + row*256 + sl*4);
  float4 hi = *(const float4*)(xb + row*256 + 128 + sl*4);

  __syncthreads();                     // cst/snt ready

  float cd[4], sd[4];
#pragma unroll
  for (int j = 0; j < 4; ++j) { cd[j] = cst[kyv[j]]; sd[j] = snt[kyv[j]]; }

  float ar[4][4], ai[4][4];
#pragma unroll
  for (int j = 0; j < 4; ++j)
#pragma unroll
    for (int r = 0; r < 4; ++r) { ar[j][r] = 0.f; ai[j][r] = 0.f; }

  bufA[XEOFF(sl*4+0) + row] = lo.x + hi.x;
  bufA[XEOFF(sl*4+1) + row] = lo.y + hi.y;
  bufA[XEOFF(sl*4+2) + row] = lo.z + hi.z;
  bufA[XEOFF(sl*4+3) + row] = lo.w + hi.w;
  bufA[XOOFF(sl*4+0) + row] = lo.x - hi.x;
  bufA[XOOFF(sl*4+1) + row] = lo.y - hi.y;
  bufA[XOOFF(sl*4+2) + row] = lo.z - hi.z;
  bufA[XOOFF(sl*4+3) + row] = lo.w - hi.w;
  __syncthreads();                     // chunk 0 staged

  const int pofs = p ? (16*260 + 8) : 0;

  for (int c = 0; c < 8; ++c) {        // ROLLED — do not unroll (spill)
    float* cur = (c & 1) ? bufB : bufA;
    float* nxt = (c & 1) ? bufA : bufB;
    if (c < 7) {
      const int w0n = (c+1) * 16;
      lo = *(const float4*)(xb + row*256 + w0n + sl*4);
      hi = *(const float4*)(xb + row*256 + w0n + 128 + sl*4);
    }
    float cc[4], sv[4];
#pragma unroll
    for (int j = 0; j < 4; ++j) {
      const int m = (kyv[j] * (c*16 + wq*4)) & 255;
      cc[j] = cst[m];
      sv[j] = snt[m];
    }
    const float* rp = cur + pofs;
#pragma unroll
    for (int i = 0; i < 4; ++i) {
      const int wl = wq*4 + i;
      const float4 xs4 = *(const float4*)&rp[wl*260 + tr*4];
#pragma unroll
      for (int j = 0; j < 4; ++j) {
        ar[j][0] += xs4.x * cc[j];  ai[j][0] -= xs4.x * sv[j];
        ar[j][1] += xs4.y * cc[j];  ai[j][1] -= xs4.y * sv[j];
        ar[j][2] += xs4.z * cc[j];  ai[j][2] -= xs4.z * sv[j];
        ar[j][3] += xs4.w * cc[j];  ai[j][3] -= xs4.w * sv[j];
        const float nc = cc[j]*cd[j] - sv[j]*sd[j];
        const float ns = sv[j]*cd[j] + cc[j]*sd[j];
        cc[j] = nc; sv[j] = ns;
      }
    }
    if (c < 7) {
      nxt[XEOFF(sl*4+0) + row] = lo.x + hi.x;
      nxt[XEOFF(sl*4+1) + row] = lo.y + hi.y;
      nxt[XEOFF(sl*4+2) + row] = lo.z + hi.z;
      nxt[XEOFF(sl*4+3) + row] = lo.w + hi.w;
      nxt[XOOFF(sl*4+0) + row] = lo.x - hi.x;
      nxt[XOOFF(sl*4+1) + row] = lo.y - hi.y;
      nxt[XOOFF(sl*4+2) + row] = lo.z - hi.z;
      nxt[XOOFF(sl*4+3) + row] = lo.w - hi.w;
    }
    __syncthreads();                   // ONE barrier per chunk
  }

#pragma unroll
  for (int j = 0; j < 4; ++j)
#pragma unroll
    for (int r = 0; r < 4; ++r) {
      ar[j][r] += __shfl_xor(ar[j][r], 1);
      ar[j][r] += __shfl_xor(ar[j][r], 2);
      ai[j][r] += __shfl_xor(ai[j][r], 1);
      ai[j][r] += __shfl_xor(ai[j][r], 2);
    }
  if (wq == 0) {
#pragma unroll
    for (int j = 0; j < 4; ++j) {
      const int ky = kyv[j];
      float4 sr; sr.x = ar[j][0]; sr.y = ar[j][1]; sr.z = ar[j][2]; sr.w = ar[j][3];
      float4 si; si.x = ai[j][0]; si.y = ai[j][1]; si.z = ai[j][2]; si.w = ai[j][3];
      *(float4*)&bufA[XEOFF(ky) + tr*4] = sr;
      *(float4*)&bufA[XOOFF(ky) + tr*4] = si;
    }
  }
  __syncthreads();

  const int ky2 = t & 15, kx = (t >> 4) & 15, hh = t >> 8;
  const float cdk = cst[kx], sdk = snt[kx];
  const int m0 = (kx * hh * 64) & 255;
  float cR = cst[m0], sR = snt[m0];
  float arr = 0.f, aii = 0.f;
  const int be = XEOFF(ky2) + hh*64;
  const int bo = XOOFF(ky2) + hh*64;
#pragma unroll 4
  for (int hq = 0; hq < 16; ++hq) {
    const float4 xr = *(const float4*)&bufA[be + hq*4];
    const float4 xi = *(const float4*)&bufA[bo + hq*4];
    {
      arr += xr.x*cR + xi.x*sR;  aii += xi.x*cR - xr.x*sR;
      const float nc = cR*cdk - sR*sdk, ns = sR*cdk + cR*sdk; cR = nc; sR = ns;
    }
    {
      arr += xr.y*cR + xi.y*sR;  aii += xi.y*cR - xr.y*sR;
      const float nc = cR*cdk - sR*sdk, ns = sR*cdk + cR*sdk; cR = nc; sR = ns;
    }
    {
      arr += xr.z*cR + xi.z*sR;  aii += xi.z*cR - xr.z*sR;
      const float nc = cR*cdk - sR*sdk, ns = sR*cdk + cR*sdk; cR = nc; sR = ns;
    }
    {
      arr += xr.w*cR + xi.w*sR;  aii += xi.w*cR - xr.w*sR;
      const float nc = cR*cdk - sR*sdk, ns = sR*cdk + cR*sdk; cR = nc; sR = ns;
    }
  }
  s2[t].x = arr; s2[t].y = aii;
  __syncthreads();
  if (t < 256) {
    float xre = s2[t].x + s2[t+256].x + s2[t+512].x + s2[t+768].x;
    float xim = s2[t].y + s2[t+256].y + s2[t+512].y + s2[t+768].y;
    ws[OF_XS_RE + img*256 + t] = xre;
    ws[OF_XS_IM + img*256 + t] = xim;
  }
}

// Stage 3 (R19-verbatim)
__global__ __launch_bounds__(256) void k3_mix(const float* __restrict__ w1r,
    const float* __restrict__ w1i, const float* __restrict__ w2r,
    const float* __restrict__ w2i, float* __restrict__ ws) {
  const int o  = blockIdx.x;     // 0..63
  const int mc = blockIdx.y;     // 0..3
  const int t  = threadIdx.x;    // 256
  const int b  = t >> 6;
  const int m  = (mc << 6) + (t & 63);
  const float* xsr = ws + OF_XS_RE;
  const float* xsi = ws + OF_XS_IM;
  float a1r=0.f, a1i=0.f, a2r=0.f, a2i=0.f;
#pragma unroll 4
  for (int i = 0; i < NCI; ++i) {
    const float xr = xsr[((b*NCI + i) << 8) + m];
    const float xi = xsi[((b*NCI + i) << 8) + m];
    const int wi = ((i*NCO + o) << 8) + m;
    const float p = w1r[wi], q = w1i[wi], u = w2r[wi], v = w2i[wi];
    a1r += xr*p - xi*q;
    a1i += xr*q + xi*p;
    a2r += xr*u - xi*v;
    a2i += xr*v + xi*u;
  }
  const int oi = ((b*NCO + o) << 8) + m;
  ws[OF_O1_RE + oi] = a1r;
  ws[OF_O1_IM + oi] = a1i;
  ws[OF_O2_RE + oi] = a2r;
  ws[OF_O2_IM + oi] = a2i;
}

// Fused stage 4+5, h/h+128 FOLDED phase A: S[h]=E+O, S[h+128]=E-O where
// E/O are the even/odd-j partial sums (the (-1)^j factor applies to BOTH
// o1 and o2 twiddles). Same j-loop reads/FMAs, parity-routed accumulation ->
// phase A per-image work halves. Grid 512 = (bo, h-half); 128 rows/block.
__global__ __launch_bounds__(256) void k45_idft(const float* __restrict__ ws,
                                                float* __restrict__ out) {
  __shared__ __align__(16) float o1r[256], o1i[256], o2r[256], o2i[256];
  __shared__ float cst[256], snt[256];
  __shared__ __align__(16) float Sr[128][20], Si[128][20];
  const int t   = threadIdx.x;
  const int bo  = blockIdx.x >> 1;
  const int hcc = blockIdx.x & 1;

  o1r[t] = ws[OF_O1_RE + bo*256 + t];
  o1i[t] = ws[OF_O1_IM + bo*256 + t];
  o2r[t] = ws[OF_O2_RE + bo*256 + t];
  o2i[t] = ws[OF_O2_IM + bo*256 + t];
  {
    float sv_, cv_;
    sincosf(TPF * (float)t * (1.0f/256.0f), &sv_, &cv_);
    cst[t] = cv_;  snt[t] = sv_;
  }
  __syncthreads();

  // ---- phase A (folded) ----
  {
    const int hl = t >> 2, kq = t & 3;     // hl 0..63
    const int h  = hcc*64 + hl;
    const float chh = cst[h], shh = snt[h];
    float c1 = 1.f, s1 = 0.f;
    const int m2i = (240 * h) & 255;
    float cB = cst[m2i], sB = snt[m2i];
    float4 srE = {0,0,0,0}, siE = {0,0,0,0};
    float4 srO = {0,0,0,0}, siO = {0,0,0,0};
#pragma unroll
    for (int j = 0; j < 16; ++j) {
      const float4 r1 = *(const float4*)&o1r[j*16 + kq*4];
      const float4 i1 = *(const float4*)&o1i[j*16 + kq*4];
      const float4 r2 = *(const float4*)&o2r[j*16 + kq*4];
      const float4 i2 = *(const float4*)&o2i[j*16 + kq*4];
      float4& sr = (j & 1) ? srO : srE;
      float4& si = (j & 1) ? siO : siE;
      sr.x += r1.x*c1 - i1.x*s1 + r2.x*cB - i2.x*sB;
      si.x += r1.x*s1 + i1.x*c1 + r2.x*sB + i2.x*cB;
      sr.y += r1.y*c1 - i1.y*s1 + r2.y*cB - i2.y*sB;
      si.y += r1.y*s1 + i1.y*c1 + r2.y*sB + i2.y*cB;
      sr.z += r1.z*c1 - i1.z*s1 + r2.z*cB - i2.z*sB;
      si.z += r1.z*s1 + i1.z*c1 + r2.z*sB + i2.z*cB;
      sr.w += r1.w*c1 - i1.w*s1 + r2.w*cB - i2.w*sB;
      si.w += r1.w*s1 + i1.w*c1 + r2.w*sB + i2.w*cB;
      const float n1c = c1*chh - s1*shh, n1s = s1*chh + c1*shh;
      const float n2c = cB*chh - sB*shh, n2s = sB*chh + cB*shh;
      c1 = n1c; s1 = n1s; cB = n2c; sB = n2s;
    }
    float4 sp, sm;
    sp.x = srE.x + srO.x; sp.y = srE.y + srO.y; sp.z = srE.z + srO.z; sp.w = srE.w + srO.w;
    sm.x = srE.x - srO.x; sm.y = srE.y - srO.y; sm.z = srE.z - srO.z; sm.w = srE.w - srO.w;
    *(float4*)&Sr[hl][kq*4]      = sp;
    *(float4*)&Sr[hl+64][kq*4]   = sm;
    sp.x = siE.x + siO.x; sp.y = siE.y + siO.y; sp.z = siE.z + siO.z; sp.w = siE.w + siO.w;
    sm.x = siE.x - siO.x; sm.y = siE.y - siO.y; sm.z = siE.z - siO.z; sm.w = siE.w - siO.w;
    *(float4*)&Si[hl][kq*4]      = sp;
    *(float4*)&Si[hl+64][kq*4]   = sm;
  }
  __syncthreads();

  // ---- phase B trig (computed after phase A to cut register liveness) ----
  const int wl = t & 31;
  float c[15], s[15], c2[15], s2[15];
#pragma unroll
  for (int k = 0; k < 15; ++k) {
    const int mi = ((k+1) * wl) & 255;
    c[k] = cst[mi];
    s[k] = snt[mi];
  }
  {
    const float R = 0.70710678118654752f;
#pragma unroll
    for (int k = 0; k < 15; ++k) {
      const int r8 = (k + 1) & 7;
      switch (r8) {
        case 0: c2[k] =  c[k];            s2[k] =  s[k];            break;
        case 1: c2[k] = (c[k]-s[k])*R;    s2[k] = (s[k]+c[k])*R;    break;
        case 2: c2[k] = -s[k];            s2[k] =  c[k];            break;
        case 3: c2[k] = -(c[k]+s[k])*R;   s2[k] = (c[k]-s[k])*R;    break;
        case 4: c2[k] = -c[k];            s2[k] = -s[k];            break;
        case 5: c2[k] = (s[k]-c[k])*R;    s2[k] = -(c[k]+s[k])*R;   break;
        case 6: c2[k] =  s[k];            s2[k] = -c[k];            break;
        default:c2[k] = (c[k]+s[k])*R;    s2[k] = (s[k]-c[k])*R;    break;
      }
    }
  }

  // ---- phase B: 128 local rows, row-paired, radix-4 x2 trig sets ----
  const int half = (t >> 5) & 1;
  const int wv = t >> 6;               // 4 waves x 32 local rows
  const float scale = 2.0f / 65536.0f;
  const size_t base256 = (size_t)bo*256 + hcc*64;
#pragma unroll 2
  for (int pr = 0; pr < 16; ++pr) {
    const int lr = wv*32 + pr*2 + half;      // local row 0..127
    const float4 a0 = *(const float4*)&Sr[lr][0];
    const float4 a1 = *(const float4*)&Sr[lr][4];
    const float4 a2 = *(const float4*)&Sr[lr][8];
    const float4 a3 = *(const float4*)&Sr[lr][12];
    const float4 b0 = *(const float4*)&Si[lr][0];
    const float4 b1 = *(const float4*)&Si[lr][4];
    const float4 b2 = *(const float4*)&Si[lr][8];
    const float4 b3 = *(const float4*)&Si[lr][12];
    const float re[16] = {a0.x,a0.y,a0.z,a0.w, a1.x,a1.y,a1.z,a1.w,
                          a2.x,a2.y,a2.z,a2.w, a3.x,a3.y,a3.z,a3.w};
    const float im[16] = {b0.x,b0.y,b0.z,b0.w, b1.x,b1.y,b1.z,b1.w,
                          b2.x,b2.y,b2.z,b2.w, b3.x,b3.y,b3.z,b3.w};
    const int grow = (lr & 63) + ((lr >> 6) << 7);   // +128 for upper half
    const size_t ob = (base256 + grow) * 256;

#pragma unroll
    for (int g = 0; g < 2; ++g) {
      const float* cc = g ? c2 : c;
      const float* ss = g ? s2 : s;
      float PA = 0.5f * re[0];
      float PB = 0.f, PC = 0.f, PD = 0.f, QB = 0.f, QD = 0.f;
#pragma unroll
      for (int k = 0; k < 15; ++k) {
        const int ky = k + 1;
        const float R = re[ky], I = im[ky];
        const int cls = ky & 3;
        if (cls == 0)      PA += R*cc[k] - I*ss[k];
        else if (cls == 1) { PB += R*cc[k] - I*ss[k];  QB += R*ss[k] + I*cc[k]; }
        else if (cls == 2) PC += R*cc[k] - I*ss[k];
        else               { PD += R*cc[k] - I*ss[k];  QD += R*ss[k] + I*cc[k]; }
      }
      const float T1 = PA + PC, T2 = PB + PD;
      const float T3 = PA - PC, T4 = QB - QD;
      const int cb = wl + g*32;
      out[ob + cb]       = (T1 + T2) * scale;
      out[ob + cb + 64]  = (T3 - T4) * scale;
      out[ob + cb + 128] = (T1 - T2) * scale;
      out[ob + cb + 192] = (T3 + T4) * scale;
    }
  }
}

extern "C" void kernel_launch(void* const* d_in, const int* in_sizes, int n_in,
                              void* d_out, int out_size, void* d_ws, size_t ws_size,
                              hipStream_t stream) {
  const float* x   = (const float*)d_in[0];
  const float* w1r = (const float*)d_in[1];
  const float* w1i = (const float*)d_in[2];
  const float* w2r = (const float*)d_in[3];
  const float* w2i = (const float*)d_in[4];
  float* out = (float*)d_out;
  float* ws  = (float*)d_ws;

  hipLaunchKernelGGL(k12_dft,  dim3(256),   dim3(1024), 0, stream, x, ws);
  hipLaunchKernelGGL(k3_mix,   dim3(64, 4), dim3(256),  0, stream, w1r, w1i, w2r, w2i, ws);
  hipLaunchKernelGGL(k45_idft, dim3(512),   dim3(256),  0, stream, ws, out);
}

// Round 22
// 55.105 us; speedup vs baseline: 1.1099x; 1.0457x over previous
//
#include <hip/hip_runtime.h>

#define NB 4
#define NCI 64
#define NCO 64
#define PLANE 65536

// workspace offsets (in floats) — trig tables computed in-kernel
#define OF_XS_RE 0
#define OF_XS_IM (OF_XS_RE + PLANE)
#define OF_O1_RE (OF_XS_IM + PLANE)
#define OF_O1_IM (OF_O1_RE + PLANE)
#define OF_O2_RE (OF_O1_IM + PLANE)
#define OF_O2_IM (OF_O2_RE + PLANE)

// stage1 LDS plane layout (per buffer)
#define XEOFF(w) ((w)*260)
#define XOOFF(w) (16*260 + 8 + (w)*260)

#define TPF 6.2831853071795864769f

// Fused stage 1+2 (R19 structure) + phase-B h/h+128 parity fold:
// even kx consume Xw[h]+Xw[h+128], odd kx Xw[h]-Xw[h+128] -> phase-B
// rotation steps and FMAs halve (same LDS reads).
__global__ __launch_bounds__(1024, 4) void k12_dft(const float* __restrict__ x,
                                                   float* __restrict__ ws) {
  __shared__ float bufA[8336], bufB[8336];
  __shared__ float cst[256], snt[256];
  __shared__ float2 s2[1024];
  const int t = threadIdx.x;
  const int img = blockIdx.x;

  if (t < 256) {
    float sv_, cv_;
    sincosf(TPF * (float)t * (1.0f/256.0f), &sv_, &cv_);
    cst[t] = cv_;  snt[t] = sv_;
  }

  const int sl = t & 3, row = t >> 2;
  const int wq = t & 3, p = (t >> 2) & 1;
  const int kg = (t >> 3) & 1, tr = t >> 4;
  int kyv[4];
#pragma unroll
  for (int j = 0; j < 4; ++j) kyv[j] = p + 8*kg + 2*j;

  const float* xb = x + (size_t)img * 65536;

  float4 lo = *(const float4*)(xb + row*256 + sl*4);
  float4 hi = *(const float4*)(xb + row*256 + 128 + sl*4);

  __syncthreads();                     // cst/snt ready

  float cd[4], sd[4];
#pragma unroll
  for (int j = 0; j < 4; ++j) { cd[j] = cst[kyv[j]]; sd[j] = snt[kyv[j]]; }

  float ar[4][4], ai[4][4];
#pragma unroll
  for (int j = 0; j < 4; ++j)
#pragma unroll
    for (int r = 0; r < 4; ++r) { ar[j][r] = 0.f; ai[j][r] = 0.f; }

  bufA[XEOFF(sl*4+0) + row] = lo.x + hi.x;
  bufA[XEOFF(sl*4+1) + row] = lo.y + hi.y;
  bufA[XEOFF(sl*4+2) + row] = lo.z + hi.z;
  bufA[XEOFF(sl*4+3) + row] = lo.w + hi.w;
  bufA[XOOFF(sl*4+0) + row] = lo.x - hi.x;
  bufA[XOOFF(sl*4+1) + row] = lo.y - hi.y;
  bufA[XOOFF(sl*4+2) + row] = lo.z - hi.z;
  bufA[XOOFF(sl*4+3) + row] = lo.w - hi.w;
  __syncthreads();                     // chunk 0 staged

  const int pofs = p ? (16*260 + 8) : 0;

  for (int c = 0; c < 8; ++c) {        // ROLLED — do not unroll (spill)
    float* cur = (c & 1) ? bufB : bufA;
    float* nxt = (c & 1) ? bufA : bufB;
    if (c < 7) {
      const int w0n = (c+1) * 16;
      lo = *(const float4*)(xb + row*256 + w0n + sl*4);
      hi = *(const float4*)(xb + row*256 + w0n + 128 + sl*4);
    }
    float cc[4], sv[4];
#pragma unroll
    for (int j = 0; j < 4; ++j) {
      const int m = (kyv[j] * (c*16 + wq*4)) & 255;
      cc[j] = cst[m];
      sv[j] = snt[m];
    }
    const float* rp = cur + pofs;
#pragma unroll
    for (int i = 0; i < 4; ++i) {
      const int wl = wq*4 + i;
      const float4 xs4 = *(const float4*)&rp[wl*260 + tr*4];
#pragma unroll
      for (int j = 0; j < 4; ++j) {
        ar[j][0] += xs4.x * cc[j];  ai[j][0] -= xs4.x * sv[j];
        ar[j][1] += xs4.y * cc[j];  ai[j][1] -= xs4.y * sv[j];
        ar[j][2] += xs4.z * cc[j];  ai[j][2] -= xs4.z * sv[j];
        ar[j][3] += xs4.w * cc[j];  ai[j][3] -= xs4.w * sv[j];
        const float nc = cc[j]*cd[j] - sv[j]*sd[j];
        const float ns = sv[j]*cd[j] + cc[j]*sd[j];
        cc[j] = nc; sv[j] = ns;
      }
    }
    if (c < 7) {
      nxt[XEOFF(sl*4+0) + row] = lo.x + hi.x;
      nxt[XEOFF(sl*4+1) + row] = lo.y + hi.y;
      nxt[XEOFF(sl*4+2) + row] = lo.z + hi.z;
      nxt[XEOFF(sl*4+3) + row] = lo.w + hi.w;
      nxt[XOOFF(sl*4+0) + row] = lo.x - hi.x;
      nxt[XOOFF(sl*4+1) + row] = lo.y - hi.y;
      nxt[XOOFF(sl*4+2) + row] = lo.z - hi.z;
      nxt[XOOFF(sl*4+3) + row] = lo.w - hi.w;
    }
    __syncthreads();                   // ONE barrier per chunk
  }

#pragma unroll
  for (int j = 0; j < 4; ++j)
#pragma unroll
    for (int r = 0; r < 4; ++r) {
      ar[j][r] += __shfl_xor(ar[j][r], 1);
      ar[j][r] += __shfl_xor(ar[j][r], 2);
      ai[j][r] += __shfl_xor(ai[j][r], 1);
      ai[j][r] += __shfl_xor(ai[j][r], 2);
    }
  if (wq == 0) {
#pragma unroll
    for (int j = 0; j < 4; ++j) {
      const int ky = kyv[j];
      float4 sr; sr.x = ar[j][0]; sr.y = ar[j][1]; sr.z = ar[j][2]; sr.w = ar[j][3];
      float4 si; si.x = ai[j][0]; si.y = ai[j][1]; si.z = ai[j][2]; si.w = ai[j][3];
      *(float4*)&bufA[XEOFF(ky) + tr*4] = sr;
      *(float4*)&bufA[XOOFF(ky) + tr*4] = si;
    }
  }
  __syncthreads();

  // phase B: h-DFT with h/h+128 parity fold.
  // thread (ky2, kx, hh in 0..3): 32 folded pairs from [hh*32, hh*32+32);
  // sigma = +1 for even kx, -1 for odd kx.
  const int ky2 = t & 15, kx = (t >> 4) & 15, hh = t >> 8;
  const float sg = (kx & 1) ? -1.f : 1.f;
  const float cdk = cst[kx], sdk = snt[kx];
  const int m0 = (kx * hh * 32) & 255;
  float cR = cst[m0], sR = snt[m0];
  float arr = 0.f, aii = 0.f;
  const int be = XEOFF(ky2) + hh*32;
  const int bo = XOOFF(ky2) + hh*32;
#pragma unroll 4
  for (int hq = 0; hq < 8; ++hq) {
    const float4 xrL = *(const float4*)&bufA[be + hq*4];
    const float4 xrH = *(const float4*)&bufA[be + 128 + hq*4];
    const float4 xiL = *(const float4*)&bufA[bo + hq*4];
    const float4 xiH = *(const float4*)&bufA[bo + 128 + hq*4];
    {
      const float xr = xrL.x + sg*xrH.x, xi = xiL.x + sg*xiH.x;
      arr += xr*cR + xi*sR;  aii += xi*cR - xr*sR;
      const float nc = cR*cdk - sR*sdk, ns = sR*cdk + cR*sdk; cR = nc; sR = ns;
    }
    {
      const float xr = xrL.y + sg*xrH.y, xi = xiL.y + sg*xiH.y;
      arr += xr*cR + xi*sR;  aii += xi*cR - xr*sR;
      const float nc = cR*cdk - sR*sdk, ns = sR*cdk + cR*sdk; cR = nc; sR = ns;
    }
    {
      const float xr = xrL.z + sg*xrH.z, xi = xiL.z + sg*xiH.z;
      arr += xr*cR + xi*sR;  aii += xi*cR - xr*sR;
      const float nc = cR*cdk - sR*sdk, ns = sR*cdk + cR*sdk; cR = nc; sR = ns;
    }
    {
      const float xr = xrL.w + sg*xrH.w, xi = xiL.w + sg*xiH.w;
      arr += xr*cR + xi*sR;  aii += xi*cR - xr*sR;
      const float nc = cR*cdk - sR*sdk, ns = sR*cdk + cR*sdk; cR = nc; sR = ns;
    }
  }
  s2[t].x = arr; s2[t].y = aii;
  __syncthreads();
  if (t < 256) {
    float xre = s2[t].x + s2[t+256].x + s2[t+512].x + s2[t+768].x;
    float xim = s2[t].y + s2[t+256].y + s2[t+512].y + s2[t+768].y;
    ws[OF_XS_RE + img*256 + t] = xre;
    ws[OF_XS_IM + img*256 + t] = xim;
  }
}

// Stage 3 (R19-verbatim)
__global__ __launch_bounds__(256) void k3_mix(const float* __restrict__ w1r,
    const float* __restrict__ w1i, const float* __restrict__ w2r,
    const float* __restrict__ w2i, float* __restrict__ ws) {
  const int o  = blockIdx.x;     // 0..63
  const int mc = blockIdx.y;     // 0..3
  const int t  = threadIdx.x;    // 256
  const int b  = t >> 6;
  const int m  = (mc << 6) + (t & 63);
  const float* xsr = ws + OF_XS_RE;
  const float* xsi = ws + OF_XS_IM;
  float a1r=0.f, a1i=0.f, a2r=0.f, a2i=0.f;
#pragma unroll 4
  for (int i = 0; i < NCI; ++i) {
    const float xr = xsr[((b*NCI + i) << 8) + m];
    const float xi = xsi[((b*NCI + i) << 8) + m];
    const int wi = ((i*NCO + o) << 8) + m;
    const float p = w1r[wi], q = w1i[wi], u = w2r[wi], v = w2i[wi];
    a1r += xr*p - xi*q;
    a1i += xr*q + xi*p;
    a2r += xr*u - xi*v;
    a2i += xr*v + xi*u;
  }
  const int oi = ((b*NCO + o) << 8) + m;
  ws[OF_O1_RE + oi] = a1r;
  ws[OF_O1_IM + oi] = a1i;
  ws[OF_O2_RE + oi] = a2r;
  ws[OF_O2_IM + oi] = a2i;
}

// Fused stage 4+5 (R21-verbatim: h/h+128 folded phase A, grid 512).
__global__ __launch_bounds__(256) void k45_idft(const float* __restrict__ ws,
                                                float* __restrict__ out) {
  __shared__ __align__(16) float o1r[256], o1i[256], o2r[256], o2i[256];
  __shared__ float cst[256], snt[256];
  __shared__ __align__(16) float Sr[128][20], Si[128][20];
  const int t   = threadIdx.x;
  const int bo  = blockIdx.x >> 1;
  const int hcc = blockIdx.x & 1;

  o1r[t] = ws[OF_O1_RE + bo*256 + t];
  o1i[t] = ws[OF_O1_IM + bo*256 + t];
  o2r[t] = ws[OF_O2_RE + bo*256 + t];
  o2i[t] = ws[OF_O2_IM + bo*256 + t];
  {
    float sv_, cv_;
    sincosf(TPF * (float)t * (1.0f/256.0f), &sv_, &cv_);
    cst[t] = cv_;  snt[t] = sv_;
  }
  __syncthreads();

  // ---- phase A (folded) ----
  {
    const int hl = t >> 2, kq = t & 3;     // hl 0..63
    const int h  = hcc*64 + hl;
    const float chh = cst[h], shh = snt[h];
    float c1 = 1.f, s1 = 0.f;
    const int m2i = (240 * h) & 255;
    float cB = cst[m2i], sB = snt[m2i];
    float4 srE = {0,0,0,0}, siE = {0,0,0,0};
    float4 srO = {0,0,0,0}, siO = {0,0,0,0};
#pragma unroll
    for (int j = 0; j < 16; ++j) {
      const float4 r1 = *(const float4*)&o1r[j*16 + kq*4];
      const float4 i1 = *(const float4*)&o1i[j*16 + kq*4];
      const float4 r2 = *(const float4*)&o2r[j*16 + kq*4];
      const float4 i2 = *(const float4*)&o2i[j*16 + kq*4];
      float4& sr = (j & 1) ? srO : srE;
      float4& si = (j & 1) ? siO : siE;
      sr.x += r1.x*c1 - i1.x*s1 + r2.x*cB - i2.x*sB;
      si.x += r1.x*s1 + i1.x*c1 + r2.x*sB + i2.x*cB;
      sr.y += r1.y*c1 - i1.y*s1 + r2.y*cB - i2.y*sB;
      si.y += r1.y*s1 + i1.y*c1 + r2.y*sB + i2.y*cB;
      sr.z += r1.z*c1 - i1.z*s1 + r2.z*cB - i2.z*sB;
      si.z += r1.z*s1 + i1.z*c1 + r2.z*sB + i2.z*cB;
      sr.w += r1.w*c1 - i1.w*s1 + r2.w*cB - i2.w*sB;
      si.w += r1.w*s1 + i1.w*c1 + r2.w*sB + i2.w*cB;
      const float n1c = c1*chh - s1*shh, n1s = s1*chh + c1*shh;
      const float n2c = cB*chh - sB*shh, n2s = sB*chh + cB*shh;
      c1 = n1c; s1 = n1s; cB = n2c; sB = n2s;
    }
    float4 sp, sm;
    sp.x = srE.x + srO.x; sp.y = srE.y + srO.y; sp.z = srE.z + srO.z; sp.w = srE.w + srO.w;
    sm.x = srE.x - srO.x; sm.y = srE.y - srO.y; sm.z = srE.z - srO.z; sm.w = srE.w - srO.w;
    *(float4*)&Sr[hl][kq*4]      = sp;
    *(float4*)&Sr[hl+64][kq*4]   = sm;
    sp.x = siE.x + siO.x; sp.y = siE.y + siO.y; sp.z = siE.z + siO.z; sp.w = siE.w + siO.w;
    sm.x = siE.x - siO.x; sm.y = siE.y - siO.y; sm.z = siE.z - siO.z; sm.w = siE.w - siO.w;
    *(float4*)&Si[hl][kq*4]      = sp;
    *(float4*)&Si[hl+64][kq*4]   = sm;
  }
  __syncthreads();

  // ---- phase B trig ----
  const int wl = t & 31;
  float c[15], s[15], c2[15], s2[15];
#pragma unroll
  for (int k = 0; k < 15; ++k) {
    const int mi = ((k+1) * wl) & 255;
    c[k] = cst[mi];
    s[k] = snt[mi];
  }
  {
    const float R = 0.70710678118654752f;
#pragma unroll
    for (int k = 0; k < 15; ++k) {
      const int r8 = (k + 1) & 7;
      switch (r8) {
        case 0: c2[k] =  c[k];            s2[k] =  s[k];            break;
        case 1: c2[k] = (c[k]-s[k])*R;    s2[k] = (s[k]+c[k])*R;    break;
        case 2: c2[k] = -s[k];            s2[k] =  c[k];            break;
        case 3: c2[k] = -(c[k]+s[k])*R;   s2[k] = (c[k]-s[k])*R;    break;
        case 4: c2[k] = -c[k];            s2[k] = -s[k];            break;
        case 5: c2[k] = (s[k]-c[k])*R;    s2[k] = -(c[k]+s[k])*R;   break;
        case 6: c2[k] =  s[k];            s2[k] = -c[k];            break;
        default:c2[k] = (c[k]+s[k])*R;    s2[k] = (s[k]-c[k])*R;    break;
      }
    }
  }

  // ---- phase B: 128 local rows, row-paired, radix-4 x2 trig sets ----
  const int half = (t >> 5) & 1;
  const int wv = t >> 6;
  const float scale = 2.0f / 65536.0f;
  const size_t base256 = (size_t)bo*256 + hcc*64;
#pragma unroll 2
  for (int pr = 0; pr < 16; ++pr) {
    const int lr = wv*32 + pr*2 + half;
    const float4 a0 = *(const float4*)&Sr[lr][0];
    const float4 a1 = *(const float4*)&Sr[lr][4];
    const float4 a2 = *(const float4*)&Sr[lr][8];
    const float4 a3 = *(const float4*)&Sr[lr][12];
    const float4 b0 = *(const float4*)&Si[lr][0];
    const float4 b1 = *(const float4*)&Si[lr][4];
    const float4 b2 = *(const float4*)&Si[lr][8];
    const float4 b3 = *(const float4*)&Si[lr][12];
    const float re[16] = {a0.x,a0.y,a0.z,a0.w, a1.x,a1.y,a1.z,a1.w,
                          a2.x,a2.y,a2.z,a2.w, a3.x,a3.y,a3.z,a3.w};
    const float im[16] = {b0.x,b0.y,b0.z,b0.w, b1.x,b1.y,b1.z,b1.w,
                          b2.x,b2.y,b2.z,b2.w, b3.x,b3.y,b3.z,b3.w};
    const int grow = (lr & 63) + ((lr >> 6) << 7);
    const size_t ob = (base256 + grow) * 256;

#pragma unroll
    for (int g = 0; g < 2; ++g) {
      const float* cc = g ? c2 : c;
      const float* ss = g ? s2 : s;
      float PA = 0.5f * re[0];
      float PB = 0.f, PC = 0.f, PD = 0.f, QB = 0.f, QD = 0.f;
#pragma unroll
      for (int k = 0; k < 15; ++k) {
        const int ky = k + 1;
        const float R = re[ky], I = im[ky];
        const int cls = ky & 3;
        if (cls == 0)      PA += R*cc[k] - I*ss[k];
        else if (cls == 1) { PB += R*cc[k] - I*ss[k];  QB += R*ss[k] + I*cc[k]; }
        else if (cls == 2) PC += R*cc[k] - I*ss[k];
        else               { PD += R*cc[k] - I*ss[k];  QD += R*ss[k] + I*cc[k]; }
      }
      const float T1 = PA + PC, T2 = PB + PD;
      const float T3 = PA - PC, T4 = QB - QD;
      const int cb = wl + g*32;
      out[ob + cb]       = (T1 + T2) * scale;
      out[ob + cb + 64]  = (T3 - T4) * scale;
      out[ob + cb + 128] = (T1 - T2) * scale;
      out[ob + cb + 192] = (T3 + T4) * scale;
    }
  }
}

extern "C" void kernel_launch(void* const* d_in, const int* in_sizes, int n_in,
                              void* d_out, int out_size, void* d_ws, size_t ws_size,
                              hipStream_t stream) {
  const float* x   = (const float*)d_in[0];
  const float* w1r = (const float*)d_in[1];
  const float* w1i = (const float*)d_in[2];
  const float* w2r = (const float*)d_in[3];
  const float* w2i = (const float*)d_in[4];
  float* out = (float*)d_out;
  float* ws  = (float*)d_ws;

  hipLaunchKernelGGL(k12_dft,  dim3(256),   dim3(1024), 0, stream, x, ws);
  hipLaunchKernelGGL(k3_mix,   dim3(64, 4), dim3(256),  0, stream, w1r, w1i, w2r, w2i, ws);
  hipLaunchKernelGGL(k45_idft, dim3(512),   dim3(256),  0, stream, ws, out);
}

// Round 23
// 54.947 us; speedup vs baseline: 1.1131x; 1.0029x over previous
//
#include <hip/hip_runtime.h>

#define NB 4
#define NCI 64
#define NCO 64
#define PLANE 65536

// workspace offsets (in floats) — trig tables computed in-kernel
#define OF_XS_RE 0
#define OF_XS_IM (OF_XS_RE + PLANE)
#define OF_O1_RE (OF_XS_IM + PLANE)
#define OF_O1_IM (OF_O1_RE + PLANE)
#define OF_O2_RE (OF_O1_IM + PLANE)
#define OF_O2_IM (OF_O2_RE + PLANE)

// stage1 LDS plane layout (per buffer)
#define XEOFF(w) ((w)*260)
#define XOOFF(w) (16*260 + 8 + (w)*260)

#define TPF 6.2831853071795864769f

// Fused stage 1+2 (R22 structure: rolled dbuf, phase-B parity fold) with a
// DEPTH-2 register prefetch ring (named slots lo0/hi0, lo1/hi1 — no dynamic
// indexing): loads for chunk c+2 issue at iter c, staged at end of iter c+1,
// so issue-to-use spans ~2 compute phases + a barrier (> HBM latency).
__global__ __launch_bounds__(1024, 4) void k12_dft(const float* __restrict__ x,
                                                   float* __restrict__ ws) {
  __shared__ float bufA[8336], bufB[8336];
  __shared__ float cst[256], snt[256];
  __shared__ float2 s2[1024];
  const int t = threadIdx.x;
  const int img = blockIdx.x;

  if (t < 256) {
    float sv_, cv_;
    sincosf(TPF * (float)t * (1.0f/256.0f), &sv_, &cv_);
    cst[t] = cv_;  snt[t] = sv_;
  }

  const int sl = t & 3, row = t >> 2;
  const int wq = t & 3, p = (t >> 2) & 1;
  const int kg = (t >> 3) & 1, tr = t >> 4;
  int kyv[4];
#pragma unroll
  for (int j = 0; j < 4; ++j) kyv[j] = p + 8*kg + 2*j;

  const float* xb = x + (size_t)img * 65536;

  // depth-2 ring prologue: chunks 0 and 1 in flight
  float4 lo0 = *(const float4*)(xb + row*256 + sl*4);
  float4 hi0 = *(const float4*)(xb + row*256 + 128 + sl*4);
  float4 lo1 = *(const float4*)(xb + row*256 + 16 + sl*4);
  float4 hi1 = *(const float4*)(xb + row*256 + 144 + sl*4);

  __syncthreads();                     // cst/snt ready

  float cd[4], sd[4];
#pragma unroll
  for (int j = 0; j < 4; ++j) { cd[j] = cst[kyv[j]]; sd[j] = snt[kyv[j]]; }

  float ar[4][4], ai[4][4];
#pragma unroll
  for (int j = 0; j < 4; ++j)
#pragma unroll
    for (int r = 0; r < 4; ++r) { ar[j][r] = 0.f; ai[j][r] = 0.f; }

  // stage chunk 0 from slot0 into bufA
  bufA[XEOFF(sl*4+0) + row] = lo0.x + hi0.x;
  bufA[XEOFF(sl*4+1) + row] = lo0.y + hi0.y;
  bufA[XEOFF(sl*4+2) + row] = lo0.z + hi0.z;
  bufA[XEOFF(sl*4+3) + row] = lo0.w + hi0.w;
  bufA[XOOFF(sl*4+0) + row] = lo0.x - hi0.x;
  bufA[XOOFF(sl*4+1) + row] = lo0.y - hi0.y;
  bufA[XOOFF(sl*4+2) + row] = lo0.z - hi0.z;
  bufA[XOOFF(sl*4+3) + row] = lo0.w - hi0.w;
  __syncthreads();                     // chunk 0 staged

  const int pofs = p ? (16*260 + 8) : 0;

  for (int c = 0; c < 8; ++c) {        // ROLLED — do not unroll (spill)
    float* cur = (c & 1) ? bufB : bufA;
    float* nxt = (c & 1) ? bufA : bufB;
    if (c < 6) {                       // issue chunk c+2 into slot (c&1)
      const int w0n = (c+2) * 16;
      if (c & 1) {
        lo1 = *(const float4*)(xb + row*256 + w0n + sl*4);
        hi1 = *(const float4*)(xb + row*256 + w0n + 128 + sl*4);
      } else {
        lo0 = *(const float4*)(xb + row*256 + w0n + sl*4);
        hi0 = *(const float4*)(xb + row*256 + w0n + 128 + sl*4);
      }
    }
    // compute chunk c from cur
    float cc[4], sv[4];
#pragma unroll
    for (int j = 0; j < 4; ++j) {
      const int m = (kyv[j] * (c*16 + wq*4)) & 255;
      cc[j] = cst[m];
      sv[j] = snt[m];
    }
    const float* rp = cur + pofs;
#pragma unroll
    for (int i = 0; i < 4; ++i) {
      const int wl = wq*4 + i;
      const float4 xs4 = *(const float4*)&rp[wl*260 + tr*4];
#pragma unroll
      for (int j = 0; j < 4; ++j) {
        ar[j][0] += xs4.x * cc[j];  ai[j][0] -= xs4.x * sv[j];
        ar[j][1] += xs4.y * cc[j];  ai[j][1] -= xs4.y * sv[j];
        ar[j][2] += xs4.z * cc[j];  ai[j][2] -= xs4.z * sv[j];
        ar[j][3] += xs4.w * cc[j];  ai[j][3] -= xs4.w * sv[j];
        const float nc = cc[j]*cd[j] - sv[j]*sd[j];
        const float ns = sv[j]*cd[j] + cc[j]*sd[j];
        cc[j] = nc; sv[j] = ns;
      }
    }
    if (c < 7) {                       // stage chunk c+1 from slot ((c+1)&1)
      if (c & 1) {
        nxt[XEOFF(sl*4+0) + row] = lo0.x + hi0.x;
        nxt[XEOFF(sl*4+1) + row] = lo0.y + hi0.y;
        nxt[XEOFF(sl*4+2) + row] = lo0.z + hi0.z;
        nxt[XEOFF(sl*4+3) + row] = lo0.w + hi0.w;
        nxt[XOOFF(sl*4+0) + row] = lo0.x - hi0.x;
        nxt[XOOFF(sl*4+1) + row] = lo0.y - hi0.y;
        nxt[XOOFF(sl*4+2) + row] = lo0.z - hi0.z;
        nxt[XOOFF(sl*4+3) + row] = lo0.w - hi0.w;
      } else {
        nxt[XEOFF(sl*4+0) + row] = lo1.x + hi1.x;
        nxt[XEOFF(sl*4+1) + row] = lo1.y + hi1.y;
        nxt[XEOFF(sl*4+2) + row] = lo1.z + hi1.z;
        nxt[XEOFF(sl*4+3) + row] = lo1.w + hi1.w;
        nxt[XOOFF(sl*4+0) + row] = lo1.x - hi1.x;
        nxt[XOOFF(sl*4+1) + row] = lo1.y - hi1.y;
        nxt[XOOFF(sl*4+2) + row] = lo1.z - hi1.z;
        nxt[XOOFF(sl*4+3) + row] = lo1.w - hi1.w;
      }
    }
    __syncthreads();                   // ONE barrier per chunk
  }

#pragma unroll
  for (int j = 0; j < 4; ++j)
#pragma unroll
    for (int r = 0; r < 4; ++r) {
      ar[j][r] += __shfl_xor(ar[j][r], 1);
      ar[j][r] += __shfl_xor(ar[j][r], 2);
      ai[j][r] += __shfl_xor(ai[j][r], 1);
      ai[j][r] += __shfl_xor(ai[j][r], 2);
    }
  if (wq == 0) {
#pragma unroll
    for (int j = 0; j < 4; ++j) {
      const int ky = kyv[j];
      float4 sr; sr.x = ar[j][0]; sr.y = ar[j][1]; sr.z = ar[j][2]; sr.w = ar[j][3];
      float4 si; si.x = ai[j][0]; si.y = ai[j][1]; si.z = ai[j][2]; si.w = ai[j][3];
      *(float4*)&bufA[XEOFF(ky) + tr*4] = sr;
      *(float4*)&bufA[XOOFF(ky) + tr*4] = si;
    }
  }
  __syncthreads();

  // phase B: h-DFT with h/h+128 parity fold (R22).
  const int ky2 = t & 15, kx = (t >> 4) & 15, hh = t >> 8;
  const float sg = (kx & 1) ? -1.f : 1.f;
  const float cdk = cst[kx], sdk = snt[kx];
  const int m0 = (kx * hh * 32) & 255;
  float cR = cst[m0], sR = snt[m0];
  float arr = 0.f, aii = 0.f;
  const int be = XEOFF(ky2) + hh*32;
  const int bo = XOOFF(ky2) + hh*32;
#pragma unroll 4
  for (int hq = 0; hq < 8; ++hq) {
    const float4 xrL = *(const float4*)&bufA[be + hq*4];
    const float4 xrH = *(const float4*)&bufA[be + 128 + hq*4];
    const float4 xiL = *(const float4*)&bufA[bo + hq*4];
    const float4 xiH = *(const float4*)&bufA[bo + 128 + hq*4];
    {
      const float xr = xrL.x + sg*xrH.x, xi = xiL.x + sg*xiH.x;
      arr += xr*cR + xi*sR;  aii += xi*cR - xr*sR;
      const float nc = cR*cdk - sR*sdk, ns = sR*cdk + cR*sdk; cR = nc; sR = ns;
    }
    {
      const float xr = xrL.y + sg*xrH.y, xi = xiL.y + sg*xiH.y;
      arr += xr*cR + xi*sR;  aii += xi*cR - xr*sR;
      const float nc = cR*cdk - sR*sdk, ns = sR*cdk + cR*sdk; cR = nc; sR = ns;
    }
    {
      const float xr = xrL.z + sg*xrH.z, xi = xiL.z + sg*xiH.z;
      arr += xr*cR + xi*sR;  aii += xi*cR - xr*sR;
      const float nc = cR*cdk - sR*sdk, ns = sR*cdk + cR*sdk; cR = nc; sR = ns;
    }
    {
      const float xr = xrL.w + sg*xrH.w, xi = xiL.w + sg*xiH.w;
      arr += xr*cR + xi*sR;  aii += xi*cR - xr*sR;
      const float nc = cR*cdk - sR*sdk, ns = sR*cdk + cR*sdk; cR = nc; sR = ns;
    }
  }
  s2[t].x = arr; s2[t].y = aii;
  __syncthreads();
  if (t < 256) {
    float xre = s2[t].x + s2[t+256].x + s2[t+512].x + s2[t+768].x;
    float xim = s2[t].y + s2[t+256].y + s2[t+512].y + s2[t+768].y;
    ws[OF_XS_RE + img*256 + t] = xre;
    ws[OF_XS_IM + img*256 + t] = xim;
  }
}

// Stage 3 (R19-verbatim)
__global__ __launch_bounds__(256) void k3_mix(const float* __restrict__ w1r,
    const float* __restrict__ w1i, const float* __restrict__ w2r,
    const float* __restrict__ w2i, float* __restrict__ ws) {
  const int o  = blockIdx.x;     // 0..63
  const int mc = blockIdx.y;     // 0..3
  const int t  = threadIdx.x;    // 256
  const int b  = t >> 6;
  const int m  = (mc << 6) + (t & 63);
  const float* xsr = ws + OF_XS_RE;
  const float* xsi = ws + OF_XS_IM;
  float a1r=0.f, a1i=0.f, a2r=0.f, a2i=0.f;
#pragma unroll 4
  for (int i = 0; i < NCI; ++i) {
    const float xr = xsr[((b*NCI + i) << 8) + m];
    const float xi = xsi[((b*NCI + i) << 8) + m];
    const int wi = ((i*NCO + o) << 8) + m;
    const float p = w1r[wi], q = w1i[wi], u = w2r[wi], v = w2i[wi];
    a1r += xr*p - xi*q;
    a1i += xr*q + xi*p;
    a2r += xr*u - xi*v;
    a2i += xr*v + xi*u;
  }
  const int oi = ((b*NCO + o) << 8) + m;
  ws[OF_O1_RE + oi] = a1r;
  ws[OF_O1_IM + oi] = a1i;
  ws[OF_O2_RE + oi] = a2r;
  ws[OF_O2_IM + oi] = a2i;
}

// Fused stage 4+5 (R22-verbatim: folded phase A, grid 512).
__global__ __launch_bounds__(256) void k45_idft(const float* __restrict__ ws,
                                                float* __restrict__ out) {
  __shared__ __align__(16) float o1r[256], o1i[256], o2r[256], o2i[256];
  __shared__ float cst[256], snt[256];
  __shared__ __align__(16) float Sr[128][20], Si[128][20];
  const int t   = threadIdx.x;
  const int bo  = blockIdx.x >> 1;
  const int hcc = blockIdx.x & 1;

  o1r[t] = ws[OF_O1_RE + bo*256 + t];
  o1i[t] = ws[OF_O1_IM + bo*256 + t];
  o2r[t] = ws[OF_O2_RE + bo*256 + t];
  o2i[t] = ws[OF_O2_IM + bo*256 + t];
  {
    float sv_, cv_;
    sincosf(TPF * (float)t * (1.0f/256.0f), &sv_, &cv_);
    cst[t] = cv_;  snt[t] = sv_;
  }
  __syncthreads();

  // ---- phase A (folded) ----
  {
    const int hl = t >> 2, kq = t & 3;     // hl 0..63
    const int h  = hcc*64 + hl;
    const float chh = cst[h], shh = snt[h];
    float c1 = 1.f, s1 = 0.f;
    const int m2i = (240 * h) & 255;
    float cB = cst[m2i], sB = snt[m2i];
    float4 srE = {0,0,0,0}, siE = {0,0,0,0};
    float4 srO = {0,0,0,0}, siO = {0,0,0,0};
#pragma unroll
    for (int j = 0; j < 16; ++j) {
      const float4 r1 = *(const float4*)&o1r[j*16 + kq*4];
      const float4 i1 = *(const float4*)&o1i[j*16 + kq*4];
      const float4 r2 = *(const float4*)&o2r[j*16 + kq*4];
      const float4 i2 = *(const float4*)&o2i[j*16 + kq*4];
      float4& sr = (j & 1) ? srO : srE;
      float4& si = (j & 1) ? siO : siE;
      sr.x += r1.x*c1 - i1.x*s1 + r2.x*cB - i2.x*sB;
      si.x += r1.x*s1 + i1.x*c1 + r2.x*sB + i2.x*cB;
      sr.y += r1.y*c1 - i1.y*s1 + r2.y*cB - i2.y*sB;
      si.y += r1.y*s1 + i1.y*c1 + r2.y*sB + i2.y*cB;
      sr.z += r1.z*c1 - i1.z*s1 + r2.z*cB - i2.z*sB;
      si.z += r1.z*s1 + i1.z*c1 + r2.z*sB + i2.z*cB;
      sr.w += r1.w*c1 - i1.w*s1 + r2.w*cB - i2.w*sB;
      si.w += r1.w*s1 + i1.w*c1 + r2.w*sB + i2.w*cB;
      const float n1c = c1*chh - s1*shh, n1s = s1*chh + c1*shh;
      const float n2c = cB*chh - sB*shh, n2s = sB*chh + cB*shh;
      c1 = n1c; s1 = n1s; cB = n2c; sB = n2s;
    }
    float4 sp, sm;
    sp.x = srE.x + srO.x; sp.y = srE.y + srO.y; sp.z = srE.z + srO.z; sp.w = srE.w + srO.w;
    sm.x = srE.x - srO.x; sm.y = srE.y - srO.y; sm.z = srE.z - srO.z; sm.w = srE.w - srO.w;
    *(float4*)&Sr[hl][kq*4]      = sp;
    *(float4*)&Sr[hl+64][kq*4]   = sm;
    sp.x = siE.x + siO.x; sp.y = siE.y + siO.y; sp.z = siE.z + siO.z; sp.w = siE.w + siO.w;
    sm.x = siE.x - siO.x; sm.y = siE.y - siO.y; sm.z = siE.z - siO.z; sm.w = siE.w - siO.w;
    *(float4*)&Si[hl][kq*4]      = sp;
    *(float4*)&Si[hl+64][kq*4]   = sm;
  }
  __syncthreads();

  // ---- phase B trig ----
  const int wl = t & 31;
  float c[15], s[15], c2[15], s2[15];
#pragma unroll
  for (int k = 0; k < 15; ++k) {
    const int mi = ((k+1) * wl) & 255;
    c[k] = cst[mi];
    s[k] = snt[mi];
  }
  {
    const float R = 0.70710678118654752f;
#pragma unroll
    for (int k = 0; k < 15; ++k) {
      const int r8 = (k + 1) & 7;
      switch (r8) {
        case 0: c2[k] =  c[k];            s2[k] =  s[k];            break;
        case 1: c2[k] = (c[k]-s[k])*R;    s2[k] = (s[k]+c[k])*R;    break;
        case 2: c2[k] = -s[k];            s2[k] =  c[k];            break;
        case 3: c2[k] = -(c[k]+s[k])*R;   s2[k] = (c[k]-s[k])*R;    break;
        case 4: c2[k] = -c[k];            s2[k] = -s[k];            break;
        case 5: c2[k] = (s[k]-c[k])*R;    s2[k] = -(c[k]+s[k])*R;   break;
        case 6: c2[k] =  s[k];            s2[k] = -c[k];            break;
        default:c2[k] = (c[k]+s[k])*R;    s2[k] = (s[k]-c[k])*R;    break;
      }
    }
  }

  // ---- phase B: 128 local rows, row-paired, radix-4 x2 trig sets ----
  const int half = (t >> 5) & 1;
  const int wv = t >> 6;
  const float scale = 2.0f / 65536.0f;
  const size_t base256 = (size_t)bo*256 + hcc*64;
#pragma unroll 2
  for (int pr = 0; pr < 16; ++pr) {
    const int lr = wv*32 + pr*2 + half;
    const float4 a0 = *(const float4*)&Sr[lr][0];
    const float4 a1 = *(const float4*)&Sr[lr][4];
    const float4 a2 = *(const float4*)&Sr[lr][8];
    const float4 a3 = *(const float4*)&Sr[lr][12];
    const float4 b0 = *(const float4*)&Si[lr][0];
    const float4 b1 = *(const float4*)&Si[lr][4];
    const float4 b2 = *(const float4*)&Si[lr][8];
    const float4 b3 = *(const float4*)&Si[lr][12];
    const float re[16] = {a0.x,a0.y,a0.z,a0.w, a1.x,a1.y,a1.z,a1.w,
                          a2.x,a2.y,a2.z,a2.w, a3.x,a3.y,a3.z,a3.w};
    const float im[16] = {b0.x,b0.y,b0.z,b0.w, b1.x,b1.y,b1.z,b1.w,
                          b2.x,b2.y,b2.z,b2.w, b3.x,b3.y,b3.z,b3.w};
    const int grow = (lr & 63) + ((lr >> 6) << 7);
    const size_t ob = (base256 + grow) * 256;

#pragma unroll
    for (int g = 0; g < 2; ++g) {
      const float* cc = g ? c2 : c;
      const float* ss = g ? s2 : s;
      float PA = 0.5f * re[0];
      float PB = 0.f, PC = 0.f, PD = 0.f, QB = 0.f, QD = 0.f;
#pragma unroll
      for (int k = 0; k < 15; ++k) {
        const int ky = k + 1;
        const float R = re[ky], I = im[ky];
        const int cls = ky & 3;
        if (cls == 0)      PA += R*cc[k] - I*ss[k];
        else if (cls == 1) { PB += R*cc[k] - I*ss[k];  QB += R*ss[k] + I*cc[k]; }
        else if (cls == 2) PC += R*cc[k] - I*ss[k];
        else               { PD += R*cc[k] - I*ss[k];  QD += R*ss[k] + I*cc[k]; }
      }
      const float T1 = PA + PC, T2 = PB + PD;
      const float T3 = PA - PC, T4 = QB - QD;
      const int cb = wl + g*32;
      out[ob + cb]       = (T1 + T2) * scale;
      out[ob + cb + 64]  = (T3 - T4) * scale;
      out[ob + cb + 128] = (T1 - T2) * scale;
      out[ob + cb + 192] = (T3 + T4) * scale;
    }
  }
}

extern "C" void kernel_launch(void* const* d_in, const int* in_sizes, int n_in,
                              void* d_out, int out_size, void* d_ws, size_t ws_size,
                              hipStream_t stream) {
  const float* x   = (const float*)d_in[0];
  const float* w1r = (const float*)d_in[1];
  const float* w1i = (const float*)d_in[2];
  const float* w2r = (const float*)d_in[3];
  const float* w2i = (const float*)d_in[4];
  float* out = (float*)d_out;
  float* ws  = (float*)d_ws;

  hipLaunchKernelGGL(k12_dft,  dim3(256),   dim3(1024), 0, stream, x, ws);
  hipLaunchKernelGGL(k3_mix,   dim3(64, 4), dim3(256),  0, stream, w1r, w1i, w2r, w2i, ws);
  hipLaunchKernelGGL(k45_idft, dim3(512),   dim3(256),  0, stream, ws, out);
}

// Round 24
// 53.313 us; speedup vs baseline: 1.1472x; 1.0307x over previous
//
#include <hip/hip_runtime.h>

#define NB 4
#define NCI 64
#define NCO 64
#define PLANE 65536

// workspace offsets (in floats)
#define OF_XS_RE 0
#define OF_XS_IM (OF_XS_RE + PLANE)

// stage1 LDS plane layout (per buffer)
#define XEOFF(w) ((w)*260)
#define XOOFF(w) (16*260 + 8 + (w)*260)

#define TPF 6.2831853071795864769f

// Fused stage 1+2 (R23-verbatim: rolled dbuf, depth-2 ring, parity-fold phase B).
__global__ __launch_bounds__(1024, 4) void k12_dft(const float* __restrict__ x,
                                                   float* __restrict__ ws) {
  __shared__ float bufA[8336], bufB[8336];
  __shared__ float cst[256], snt[256];
  __shared__ float2 s2[1024];
  const int t = threadIdx.x;
  const int img = blockIdx.x;

  if (t < 256) {
    float sv_, cv_;
    sincosf(TPF * (float)t * (1.0f/256.0f), &sv_, &cv_);
    cst[t] = cv_;  snt[t] = sv_;
  }

  const int sl = t & 3, row = t >> 2;
  const int wq = t & 3, p = (t >> 2) & 1;
  const int kg = (t >> 3) & 1, tr = t >> 4;
  int kyv[4];
#pragma unroll
  for (int j = 0; j < 4; ++j) kyv[j] = p + 8*kg + 2*j;

  const float* xb = x + (size_t)img * 65536;

  float4 lo0 = *(const float4*)(xb + row*256 + sl*4);
  float4 hi0 = *(const float4*)(xb + row*256 + 128 + sl*4);
  float4 lo1 = *(const float4*)(xb + row*256 + 16 + sl*4);
  float4 hi1 = *(const float4*)(xb + row*256 + 144 + sl*4);

  __syncthreads();                     // cst/snt ready

  float cd[4], sd[4];
#pragma unroll
  for (int j = 0; j < 4; ++j) { cd[j] = cst[kyv[j]]; sd[j] = snt[kyv[j]]; }

  float ar[4][4], ai[4][4];
#pragma unroll
  for (int j = 0; j < 4; ++j)
#pragma unroll
    for (int r = 0; r < 4; ++r) { ar[j][r] = 0.f; ai[j][r] = 0.f; }

  bufA[XEOFF(sl*4+0) + row] = lo0.x + hi0.x;
  bufA[XEOFF(sl*4+1) + row] = lo0.y + hi0.y;
  bufA[XEOFF(sl*4+2) + row] = lo0.z + hi0.z;
  bufA[XEOFF(sl*4+3) + row] = lo0.w + hi0.w;
  bufA[XOOFF(sl*4+0) + row] = lo0.x - hi0.x;
  bufA[XOOFF(sl*4+1) + row] = lo0.y - hi0.y;
  bufA[XOOFF(sl*4+2) + row] = lo0.z - hi0.z;
  bufA[XOOFF(sl*4+3) + row] = lo0.w - hi0.w;
  __syncthreads();                     // chunk 0 staged

  const int pofs = p ? (16*260 + 8) : 0;

  for (int c = 0; c < 8; ++c) {        // ROLLED — do not unroll (spill)
    float* cur = (c & 1) ? bufB : bufA;
    float* nxt = (c & 1) ? bufA : bufB;
    if (c < 6) {                       // issue chunk c+2 into slot (c&1)
      const int w0n = (c+2) * 16;
      if (c & 1) {
        lo1 = *(const float4*)(xb + row*256 + w0n + sl*4);
        hi1 = *(const float4*)(xb + row*256 + w0n + 128 + sl*4);
      } else {
        lo0 = *(const float4*)(xb + row*256 + w0n + sl*4);
        hi0 = *(const float4*)(xb + row*256 + w0n + 128 + sl*4);
      }
    }
    float cc[4], sv[4];
#pragma unroll
    for (int j = 0; j < 4; ++j) {
      const int m = (kyv[j] * (c*16 + wq*4)) & 255;
      cc[j] = cst[m];
      sv[j] = snt[m];
    }
    const float* rp = cur + pofs;
#pragma unroll
    for (int i = 0; i < 4; ++i) {
      const int wl = wq*4 + i;
      const float4 xs4 = *(const float4*)&rp[wl*260 + tr*4];
#pragma unroll
      for (int j = 0; j < 4; ++j) {
        ar[j][0] += xs4.x * cc[j];  ai[j][0] -= xs4.x * sv[j];
        ar[j][1] += xs4.y * cc[j];  ai[j][1] -= xs4.y * sv[j];
        ar[j][2] += xs4.z * cc[j];  ai[j][2] -= xs4.z * sv[j];
        ar[j][3] += xs4.w * cc[j];  ai[j][3] -= xs4.w * sv[j];
        const float nc = cc[j]*cd[j] - sv[j]*sd[j];
        const float ns = sv[j]*cd[j] + cc[j]*sd[j];
        cc[j] = nc; sv[j] = ns;
      }
    }
    if (c < 7) {
      if (c & 1) {
        nxt[XEOFF(sl*4+0) + row] = lo0.x + hi0.x;
        nxt[XEOFF(sl*4+1) + row] = lo0.y + hi0.y;
        nxt[XEOFF(sl*4+2) + row] = lo0.z + hi0.z;
        nxt[XEOFF(sl*4+3) + row] = lo0.w + hi0.w;
        nxt[XOOFF(sl*4+0) + row] = lo0.x - hi0.x;
        nxt[XOOFF(sl*4+1) + row] = lo0.y - hi0.y;
        nxt[XOOFF(sl*4+2) + row] = lo0.z - hi0.z;
        nxt[XOOFF(sl*4+3) + row] = lo0.w - hi0.w;
      } else {
        nxt[XEOFF(sl*4+0) + row] = lo1.x + hi1.x;
        nxt[XEOFF(sl*4+1) + row] = lo1.y + hi1.y;
        nxt[XEOFF(sl*4+2) + row] = lo1.z + hi1.z;
        nxt[XEOFF(sl*4+3) + row] = lo1.w + hi1.w;
        nxt[XOOFF(sl*4+0) + row] = lo1.x - hi1.x;
        nxt[XOOFF(sl*4+1) + row] = lo1.y - hi1.y;
        nxt[XOOFF(sl*4+2) + row] = lo1.z - hi1.z;
        nxt[XOOFF(sl*4+3) + row] = lo1.w - hi1.w;
      }
    }
    __syncthreads();                   // ONE barrier per chunk
  }

#pragma unroll
  for (int j = 0; j < 4; ++j)
#pragma unroll
    for (int r = 0; r < 4; ++r) {
      ar[j][r] += __shfl_xor(ar[j][r], 1);
      ar[j][r] += __shfl_xor(ar[j][r], 2);
      ai[j][r] += __shfl_xor(ai[j][r], 1);
      ai[j][r] += __shfl_xor(ai[j][r], 2);
    }
  if (wq == 0) {
#pragma unroll
    for (int j = 0; j < 4; ++j) {
      const int ky = kyv[j];
      float4 sr; sr.x = ar[j][0]; sr.y = ar[j][1]; sr.z = ar[j][2]; sr.w = ar[j][3];
      float4 si; si.x = ai[j][0]; si.y = ai[j][1]; si.z = ai[j][2]; si.w = ai[j][3];
      *(float4*)&bufA[XEOFF(ky) + tr*4] = sr;
      *(float4*)&bufA[XOOFF(ky) + tr*4] = si;
    }
  }
  __syncthreads();

  // phase B: h-DFT with h/h+128 parity fold.
  const int ky2 = t & 15, kx = (t >> 4) & 15, hh = t >> 8;
  const float sg = (kx & 1) ? -1.f : 1.f;
  const float cdk = cst[kx], sdk = snt[kx];
  const int m0 = (kx * hh * 32) & 255;
  float cR = cst[m0], sR = snt[m0];
  float arr = 0.f, aii = 0.f;
  const int be = XEOFF(ky2) + hh*32;
  const int bo = XOOFF(ky2) + hh*32;
#pragma unroll 4
  for (int hq = 0; hq < 8; ++hq) {
    const float4 xrL = *(const float4*)&bufA[be + hq*4];
    const float4 xrH = *(const float4*)&bufA[be + 128 + hq*4];
    const float4 xiL = *(const float4*)&bufA[bo + hq*4];
    const float4 xiH = *(const float4*)&bufA[bo + 128 + hq*4];
    {
      const float xr = xrL.x + sg*xrH.x, xi = xiL.x + sg*xiH.x;
      arr += xr*cR + xi*sR;  aii += xi*cR - xr*sR;
      const float nc = cR*cdk - sR*sdk, ns = sR*cdk + cR*sdk; cR = nc; sR = ns;
    }
    {
      const float xr = xrL.y + sg*xrH.y, xi = xiL.y + sg*xiH.y;
      arr += xr*cR + xi*sR;  aii += xi*cR - xr*sR;
      const float nc = cR*cdk - sR*sdk, ns = sR*cdk + cR*sdk; cR = nc; sR = ns;
    }
    {
      const float xr = xrL.z + sg*xrH.z, xi = xiL.z + sg*xiH.z;
      arr += xr*cR + xi*sR;  aii += xi*cR - xr*sR;
      const float nc = cR*cdk - sR*sdk, ns = sR*cdk + cR*sdk; cR = nc; sR = ns;
    }
    {
      const float xr = xrL.w + sg*xrH.w, xi = xiL.w + sg*xiH.w;
      arr += xr*cR + xi*sR;  aii += xi*cR - xr*sR;
      const float nc = cR*cdk - sR*sdk, ns = sR*cdk + cR*sdk; cR = nc; sR = ns;
    }
  }
  s2[t].x = arr; s2[t].y = aii;
  __syncthreads();
  if (t < 256) {
    float xre = s2[t].x + s2[t+256].x + s2[t+512].x + s2[t+768].x;
    float xim = s2[t].y + s2[t+256].y + s2[t+512].y + s2[t+768].y;
    ws[OF_XS_RE + img*256 + t] = xre;
    ws[OF_XS_IM + img*256 + t] = xim;
  }
}

// Fused stage 3+4+5: per block (bo, hcc):
//  phase 0: channel mix for this bo in-block (k3 eliminated)
//  phase A: h/h+128 folded S computation
//  phase B: row-paired radix-4 inverse w-DFT + store
__global__ __launch_bounds__(256) void k345_idft(const float* __restrict__ w1r,
    const float* __restrict__ w1i, const float* __restrict__ w2r,
    const float* __restrict__ w2i, const float* __restrict__ ws,
    float* __restrict__ out) {
  __shared__ __align__(16) float o1r[256], o1i[256], o2r[256], o2i[256];
  __shared__ float cst[256], snt[256];
  __shared__ __align__(16) float Sr[128][20], Si[128][20];
  const int t   = threadIdx.x;
  const int bo  = blockIdx.x >> 1;
  const int hcc = blockIdx.x & 1;

  {
    float sv_, cv_;
    sincosf(TPF * (float)t * (1.0f/256.0f), &sv_, &cv_);
    cst[t] = cv_;  snt[t] = sv_;
  }

  // ---- phase 0: mix (thread t = mode m) ----
  {
    const int b = bo >> 6, o = bo & 63;
    const float* xsr = ws + OF_XS_RE;
    const float* xsi = ws + OF_XS_IM;
    float a1r=0.f, a1i=0.f, a2r=0.f, a2i=0.f;
#pragma unroll 4
    for (int i = 0; i < NCI; ++i) {
      const int xi_ = ((b*NCI + i) << 8) + t;
      const float xr = xsr[xi_];
      const float xi = xsi[xi_];
      const int wi = ((i*NCO + o) << 8) + t;
      const float pw = w1r[wi], q = w1i[wi], u = w2r[wi], v = w2i[wi];
      a1r += xr*pw - xi*q;
      a1i += xr*q + xi*pw;
      a2r += xr*u - xi*v;
      a2i += xr*v + xi*u;
    }
    o1r[t] = a1r;
    o1i[t] = a1i;
    o2r[t] = a2r;
    o2i[t] = a2i;
  }
  __syncthreads();

  // ---- phase A (folded) ----
  {
    const int hl = t >> 2, kq = t & 3;     // hl 0..63
    const int h  = hcc*64 + hl;
    const float chh = cst[h], shh = snt[h];
    float c1 = 1.f, s1 = 0.f;
    const int m2i = (240 * h) & 255;
    float cB = cst[m2i], sB = snt[m2i];
    float4 srE = {0,0,0,0}, siE = {0,0,0,0};
    float4 srO = {0,0,0,0}, siO = {0,0,0,0};
#pragma unroll
    for (int j = 0; j < 16; ++j) {
      const float4 r1 = *(const float4*)&o1r[j*16 + kq*4];
      const float4 i1 = *(const float4*)&o1i[j*16 + kq*4];
      const float4 r2 = *(const float4*)&o2r[j*16 + kq*4];
      const float4 i2 = *(const float4*)&o2i[j*16 + kq*4];
      float4& sr = (j & 1) ? srO : srE;
      float4& si = (j & 1) ? siO : siE;
      sr.x += r1.x*c1 - i1.x*s1 + r2.x*cB - i2.x*sB;
      si.x += r1.x*s1 + i1.x*c1 + r2.x*sB + i2.x*cB;
      sr.y += r1.y*c1 - i1.y*s1 + r2.y*cB - i2.y*sB;
      si.y += r1.y*s1 + i1.y*c1 + r2.y*sB + i2.y*cB;
      sr.z += r1.z*c1 - i1.z*s1 + r2.z*cB - i2.z*sB;
      si.z += r1.z*s1 + i1.z*c1 + r2.z*sB + i2.z*cB;
      sr.w += r1.w*c1 - i1.w*s1 + r2.w*cB - i2.w*sB;
      si.w += r1.w*s1 + i1.w*c1 + r2.w*sB + i2.w*cB;
      const float n1c = c1*chh - s1*shh, n1s = s1*chh + c1*shh;
      const float n2c = cB*chh - sB*shh, n2s = sB*chh + cB*shh;
      c1 = n1c; s1 = n1s; cB = n2c; sB = n2s;
    }
    float4 sp, sm;
    sp.x = srE.x + srO.x; sp.y = srE.y + srO.y; sp.z = srE.z + srO.z; sp.w = srE.w + srO.w;
    sm.x = srE.x - srO.x; sm.y = srE.y - srO.y; sm.z = srE.z - srO.z; sm.w = srE.w - srO.w;
    *(float4*)&Sr[hl][kq*4]      = sp;
    *(float4*)&Sr[hl+64][kq*4]   = sm;
    sp.x = siE.x + siO.x; sp.y = siE.y + siO.y; sp.z = siE.z + siO.z; sp.w = siE.w + siO.w;
    sm.x = siE.x - siO.x; sm.y = siE.y - siO.y; sm.z = siE.z - siO.z; sm.w = siE.w - siO.w;
    *(float4*)&Si[hl][kq*4]      = sp;
    *(float4*)&Si[hl+64][kq*4]   = sm;
  }
  __syncthreads();

  // ---- phase B trig ----
  const int wl = t & 31;
  float c[15], s[15], c2[15], s2[15];
#pragma unroll
  for (int k = 0; k < 15; ++k) {
    const int mi = ((k+1) * wl) & 255;
    c[k] = cst[mi];
    s[k] = snt[mi];
  }
  {
    const float R = 0.70710678118654752f;
#pragma unroll
    for (int k = 0; k < 15; ++k) {
      const int r8 = (k + 1) & 7;
      switch (r8) {
        case 0: c2[k] =  c[k];            s2[k] =  s[k];            break;
        case 1: c2[k] = (c[k]-s[k])*R;    s2[k] = (s[k]+c[k])*R;    break;
        case 2: c2[k] = -s[k];            s2[k] =  c[k];            break;
        case 3: c2[k] = -(c[k]+s[k])*R;   s2[k] = (c[k]-s[k])*R;    break;
        case 4: c2[k] = -c[k];            s2[k] = -s[k];            break;
        case 5: c2[k] = (s[k]-c[k])*R;    s2[k] = -(c[k]+s[k])*R;   break;
        case 6: c2[k] =  s[k];            s2[k] = -c[k];            break;
        default:c2[k] = (c[k]+s[k])*R;    s2[k] = (s[k]-c[k])*R;    break;
      }
    }
  }

  // ---- phase B: 128 local rows, row-paired, radix-4 x2 trig sets ----
  const int half = (t >> 5) & 1;
  const int wv = t >> 6;
  const float scale = 2.0f / 65536.0f;
  const size_t base256 = (size_t)bo*256 + hcc*64;
#pragma unroll 2
  for (int pr = 0; pr < 16; ++pr) {
    const int lr = wv*32 + pr*2 + half;
    const float4 a0 = *(const float4*)&Sr[lr][0];
    const float4 a1 = *(const float4*)&Sr[lr][4];
    const float4 a2 = *(const float4*)&Sr[lr][8];
    const float4 a3 = *(const float4*)&Sr[lr][12];
    const float4 b0 = *(const float4*)&Si[lr][0];
    const float4 b1 = *(const float4*)&Si[lr][4];
    const float4 b2 = *(const float4*)&Si[lr][8];
    const float4 b3 = *(const float4*)&Si[lr][12];
    const float re[16] = {a0.x,a0.y,a0.z,a0.w, a1.x,a1.y,a1.z,a1.w,
                          a2.x,a2.y,a2.z,a2.w, a3.x,a3.y,a3.z,a3.w};
    const float im[16] = {b0.x,b0.y,b0.z,b0.w, b1.x,b1.y,b1.z,b1.w,
                          b2.x,b2.y,b2.z,b2.w, b3.x,b3.y,b3.z,b3.w};
    const int grow = (lr & 63) + ((lr >> 6) << 7);
    const size_t ob = (base256 + grow) * 256;

#pragma unroll
    for (int g = 0; g < 2; ++g) {
      const float* cc = g ? c2 : c;
      const float* ss = g ? s2 : s;
      float PA = 0.5f * re[0];
      float PB = 0.f, PC = 0.f, PD = 0.f, QB = 0.f, QD = 0.f;
#pragma unroll
      for (int k = 0; k < 15; ++k) {
        const int ky = k + 1;
        const float R = re[ky], I = im[ky];
        const int cls = ky & 3;
        if (cls == 0)      PA += R*cc[k] - I*ss[k];
        else if (cls == 1) { PB += R*cc[k] - I*ss[k];  QB += R*ss[k] + I*cc[k]; }
        else if (cls == 2) PC += R*cc[k] - I*ss[k];
        else               { PD += R*cc[k] - I*ss[k];  QD += R*ss[k] + I*cc[k]; }
      }
      const float T1 = PA + PC, T2 = PB + PD;
      const float T3 = PA - PC, T4 = QB - QD;
      const int cb = wl + g*32;
      out[ob + cb]       = (T1 + T2) * scale;
      out[ob + cb + 64]  = (T3 - T4) * scale;
      out[ob + cb + 128] = (T1 - T2) * scale;
      out[ob + cb + 192] = (T3 + T4) * scale;
    }
  }
}

extern "C" void kernel_launch(void* const* d_in, const int* in_sizes, int n_in,
                              void* d_out, int out_size, void* d_ws, size_t ws_size,
                              hipStream_t stream) {
  const float* x   = (const float*)d_in[0];
  const float* w1r = (const float*)d_in[1];
  const float* w1i = (const float*)d_in[2];
  const float* w2r = (const float*)d_in[3];
  const float* w2i = (const float*)d_in[4];
  float* out = (float*)d_out;
  float* ws  = (float*)d_ws;

  hipLaunchKernelGGL(k12_dft,   dim3(256), dim3(1024), 0, stream, x, ws);
  hipLaunchKernelGGL(k345_idft, dim3(512), dim3(256),  0, stream,
                     w1r, w1i, w2r, w2i, ws, out);
}

// Round 25
// 49.776 us; speedup vs baseline: 1.2288x; 1.0711x over previous
//
#include <hip/hip_runtime.h>

#define NB 4
#define NCI 64
#define NCO 64
#define PLANE 65536

// workspace offsets (in floats)
#define OF_XS_RE 0
#define OF_XS_IM (OF_XS_RE + PLANE)

// stage1 LDS plane layout (per buffer)
#define XEOFF(w) ((w)*260)
#define XOOFF(w) (16*260 + 8 + (w)*260)

#define TPF 6.2831853071795864769f

// Fused stage 1+2 (R23-verbatim: rolled dbuf, depth-2 ring, parity-fold phase B).
__global__ __launch_bounds__(1024, 4) void k12_dft(const float* __restrict__ x,
                                                   float* __restrict__ ws) {
  __shared__ float bufA[8336], bufB[8336];
  __shared__ float cst[256], snt[256];
  __shared__ float2 s2[1024];
  const int t = threadIdx.x;
  const int img = blockIdx.x;

  if (t < 256) {
    float sv_, cv_;
    sincosf(TPF * (float)t * (1.0f/256.0f), &sv_, &cv_);
    cst[t] = cv_;  snt[t] = sv_;
  }

  const int sl = t & 3, row = t >> 2;
  const int wq = t & 3, p = (t >> 2) & 1;
  const int kg = (t >> 3) & 1, tr = t >> 4;
  int kyv[4];
#pragma unroll
  for (int j = 0; j < 4; ++j) kyv[j] = p + 8*kg + 2*j;

  const float* xb = x + (size_t)img * 65536;

  float4 lo0 = *(const float4*)(xb + row*256 + sl*4);
  float4 hi0 = *(const float4*)(xb + row*256 + 128 + sl*4);
  float4 lo1 = *(const float4*)(xb + row*256 + 16 + sl*4);
  float4 hi1 = *(const float4*)(xb + row*256 + 144 + sl*4);

  __syncthreads();                     // cst/snt ready

  float cd[4], sd[4];
#pragma unroll
  for (int j = 0; j < 4; ++j) { cd[j] = cst[kyv[j]]; sd[j] = snt[kyv[j]]; }

  float ar[4][4], ai[4][4];
#pragma unroll
  for (int j = 0; j < 4; ++j)
#pragma unroll
    for (int r = 0; r < 4; ++r) { ar[j][r] = 0.f; ai[j][r] = 0.f; }

  bufA[XEOFF(sl*4+0) + row] = lo0.x + hi0.x;
  bufA[XEOFF(sl*4+1) + row] = lo0.y + hi0.y;
  bufA[XEOFF(sl*4+2) + row] = lo0.z + hi0.z;
  bufA[XEOFF(sl*4+3) + row] = lo0.w + hi0.w;
  bufA[XOOFF(sl*4+0) + row] = lo0.x - hi0.x;
  bufA[XOOFF(sl*4+1) + row] = lo0.y - hi0.y;
  bufA[XOOFF(sl*4+2) + row] = lo0.z - hi0.z;
  bufA[XOOFF(sl*4+3) + row] = lo0.w - hi0.w;
  __syncthreads();                     // chunk 0 staged

  const int pofs = p ? (16*260 + 8) : 0;

  for (int c = 0; c < 8; ++c) {        // ROLLED — do not unroll (spill)
    float* cur = (c & 1) ? bufB : bufA;
    float* nxt = (c & 1) ? bufA : bufB;
    if (c < 6) {                       // issue chunk c+2 into slot (c&1)
      const int w0n = (c+2) * 16;
      if (c & 1) {
        lo1 = *(const float4*)(xb + row*256 + w0n + sl*4);
        hi1 = *(const float4*)(xb + row*256 + w0n + 128 + sl*4);
      } else {
        lo0 = *(const float4*)(xb + row*256 + w0n + sl*4);
        hi0 = *(const float4*)(xb + row*256 + w0n + 128 + sl*4);
      }
    }
    float cc[4], sv[4];
#pragma unroll
    for (int j = 0; j < 4; ++j) {
      const int m = (kyv[j] * (c*16 + wq*4)) & 255;
      cc[j] = cst[m];
      sv[j] = snt[m];
    }
    const float* rp = cur + pofs;
#pragma unroll
    for (int i = 0; i < 4; ++i) {
      const int wl = wq*4 + i;
      const float4 xs4 = *(const float4*)&rp[wl*260 + tr*4];
#pragma unroll
      for (int j = 0; j < 4; ++j) {
        ar[j][0] += xs4.x * cc[j];  ai[j][0] -= xs4.x * sv[j];
        ar[j][1] += xs4.y * cc[j];  ai[j][1] -= xs4.y * sv[j];
        ar[j][2] += xs4.z * cc[j];  ai[j][2] -= xs4.z * sv[j];
        ar[j][3] += xs4.w * cc[j];  ai[j][3] -= xs4.w * sv[j];
        const float nc = cc[j]*cd[j] - sv[j]*sd[j];
        const float ns = sv[j]*cd[j] + cc[j]*sd[j];
        cc[j] = nc; sv[j] = ns;
      }
    }
    if (c < 7) {
      if (c & 1) {
        nxt[XEOFF(sl*4+0) + row] = lo0.x + hi0.x;
        nxt[XEOFF(sl*4+1) + row] = lo0.y + hi0.y;
        nxt[XEOFF(sl*4+2) + row] = lo0.z + hi0.z;
        nxt[XEOFF(sl*4+3) + row] = lo0.w + hi0.w;
        nxt[XOOFF(sl*4+0) + row] = lo0.x - hi0.x;
        nxt[XOOFF(sl*4+1) + row] = lo0.y - hi0.y;
        nxt[XOOFF(sl*4+2) + row] = lo0.z - hi0.z;
        nxt[XOOFF(sl*4+3) + row] = lo0.w - hi0.w;
      } else {
        nxt[XEOFF(sl*4+0) + row] = lo1.x + hi1.x;
        nxt[XEOFF(sl*4+1) + row] = lo1.y + hi1.y;
        nxt[XEOFF(sl*4+2) + row] = lo1.z + hi1.z;
        nxt[XEOFF(sl*4+3) + row] = lo1.w + hi1.w;
        nxt[XOOFF(sl*4+0) + row] = lo1.x - hi1.x;
        nxt[XOOFF(sl*4+1) + row] = lo1.y - hi1.y;
        nxt[XOOFF(sl*4+2) + row] = lo1.z - hi1.z;
        nxt[XOOFF(sl*4+3) + row] = lo1.w - hi1.w;
      }
    }
    __syncthreads();                   // ONE barrier per chunk
  }

#pragma unroll
  for (int j = 0; j < 4; ++j)
#pragma unroll
    for (int r = 0; r < 4; ++r) {
      ar[j][r] += __shfl_xor(ar[j][r], 1);
      ar[j][r] += __shfl_xor(ar[j][r], 2);
      ai[j][r] += __shfl_xor(ai[j][r], 1);
      ai[j][r] += __shfl_xor(ai[j][r], 2);
    }
  if (wq == 0) {
#pragma unroll
    for (int j = 0; j < 4; ++j) {
      const int ky = kyv[j];
      float4 sr; sr.x = ar[j][0]; sr.y = ar[j][1]; sr.z = ar[j][2]; sr.w = ar[j][3];
      float4 si; si.x = ai[j][0]; si.y = ai[j][1]; si.z = ai[j][2]; si.w = ai[j][3];
      *(float4*)&bufA[XEOFF(ky) + tr*4] = sr;
      *(float4*)&bufA[XOOFF(ky) + tr*4] = si;
    }
  }
  __syncthreads();

  // phase B: h-DFT with h/h+128 parity fold.
  const int ky2 = t & 15, kx = (t >> 4) & 15, hh = t >> 8;
  const float sg = (kx & 1) ? -1.f : 1.f;
  const float cdk = cst[kx], sdk = snt[kx];
  const int m0 = (kx * hh * 32) & 255;
  float cR = cst[m0], sR = snt[m0];
  float arr = 0.f, aii = 0.f;
  const int be = XEOFF(ky2) + hh*32;
  const int bo = XOOFF(ky2) + hh*32;
#pragma unroll 4
  for (int hq = 0; hq < 8; ++hq) {
    const float4 xrL = *(const float4*)&bufA[be + hq*4];
    const float4 xrH = *(const float4*)&bufA[be + 128 + hq*4];
    const float4 xiL = *(const float4*)&bufA[bo + hq*4];
    const float4 xiH = *(const float4*)&bufA[bo + 128 + hq*4];
    {
      const float xr = xrL.x + sg*xrH.x, xi = xiL.x + sg*xiH.x;
      arr += xr*cR + xi*sR;  aii += xi*cR - xr*sR;
      const float nc = cR*cdk - sR*sdk, ns = sR*cdk + cR*sdk; cR = nc; sR = ns;
    }
    {
      const float xr = xrL.y + sg*xrH.y, xi = xiL.y + sg*xiH.y;
      arr += xr*cR + xi*sR;  aii += xi*cR - xr*sR;
      const float nc = cR*cdk - sR*sdk, ns = sR*cdk + cR*sdk; cR = nc; sR = ns;
    }
    {
      const float xr = xrL.z + sg*xrH.z, xi = xiL.z + sg*xiH.z;
      arr += xr*cR + xi*sR;  aii += xi*cR - xr*sR;
      const float nc = cR*cdk - sR*sdk, ns = sR*cdk + cR*sdk; cR = nc; sR = ns;
    }
    {
      const float xr = xrL.w + sg*xrH.w, xi = xiL.w + sg*xiH.w;
      arr += xr*cR + xi*sR;  aii += xi*cR - xr*sR;
      const float nc = cR*cdk - sR*sdk, ns = sR*cdk + cR*sdk; cR = nc; sR = ns;
    }
  }
  s2[t].x = arr; s2[t].y = aii;
  __syncthreads();
  if (t < 256) {
    float xre = s2[t].x + s2[t+256].x + s2[t+512].x + s2[t+768].x;
    float xim = s2[t].y + s2[t+256].y + s2[t+512].y + s2[t+768].y;
    ws[OF_XS_RE + img*256 + t] = xre;
    ws[OF_XS_IM + img*256 + t] = xim;
  }
}

// Fused stage 3+4+5, ONE block per bo (grid 256, 512 threads): mix computed
// once (weights read once), folded phase A over all 128 h-pairs (512 = 128x4
// exact fit), phase B = 8 waves x 32 rows.
__global__ __launch_bounds__(512, 2) void k345_idft(const float* __restrict__ w1r,
    const float* __restrict__ w1i, const float* __restrict__ w2r,
    const float* __restrict__ w2i, const float* __restrict__ ws,
    float* __restrict__ out) {
  __shared__ __align__(16) float o1r[256], o1i[256], o2r[256], o2i[256];
  __shared__ float cst[256], snt[256];
  __shared__ __align__(16) float Sr[256][20], Si[256][20];
  const int t  = threadIdx.x;
  const int bo = blockIdx.x;

  if (t < 256) {
    float sv_, cv_;
    sincosf(TPF * (float)t * (1.0f/256.0f), &sv_, &cv_);
    cst[t] = cv_;  snt[t] = sv_;
  }

  // ---- phase 0: mix, i-range split across thread halves ----
  {
    const int m = t & 255, ih = t >> 8;        // ih 0..1
    const int b = bo >> 6, o = bo & 63;
    const float* xsr = ws + OF_XS_RE;
    const float* xsi = ws + OF_XS_IM;
    float a1r=0.f, a1i=0.f, a2r=0.f, a2i=0.f;
#pragma unroll 4
    for (int ii = 0; ii < 32; ++ii) {
      const int i = ih*32 + ii;
      const int xi_ = ((b*NCI + i) << 8) + m;
      const float xr = xsr[xi_];
      const float xi = xsi[xi_];
      const int wi = ((i*NCO + o) << 8) + m;
      const float pw = w1r[wi], q = w1i[wi], u = w2r[wi], v = w2i[wi];
      a1r += xr*pw - xi*q;
      a1i += xr*q + xi*pw;
      a2r += xr*u - xi*v;
      a2i += xr*v + xi*u;
    }
    float4* pm1 = (float4*)&Sr[0][0];          // overlay (dead until phase A)
    float4* pm2 = (float4*)&Si[0][0];
    float4 v1; v1.x = a1r; v1.y = a1i; v1.z = 0.f; v1.w = 0.f;
    float4 v2; v2.x = a2r; v2.y = a2i; v2.z = 0.f; v2.w = 0.f;
    pm1[t] = v1;
    pm2[t] = v2;
  }
  __syncthreads();
  if (t < 256) {
    const float4* pm1 = (const float4*)&Sr[0][0];
    const float4* pm2 = (const float4*)&Si[0][0];
    const float4 a = pm1[t], b4 = pm1[t + 256];
    const float4 c4 = pm2[t], d4 = pm2[t + 256];
    o1r[t] = a.x + b4.x;
    o1i[t] = a.y + b4.y;
    o2r[t] = c4.x + d4.x;
    o2i[t] = c4.y + d4.y;
  }
  __syncthreads();

  // ---- phase A (folded, h = 0..127) ----
  {
    const int h = t >> 2, kq = t & 3;          // h 0..127
    const float chh = cst[h], shh = snt[h];
    float c1 = 1.f, s1 = 0.f;
    const int m2i = (240 * h) & 255;
    float cB = cst[m2i], sB = snt[m2i];
    float4 srE = {0,0,0,0}, siE = {0,0,0,0};
    float4 srO = {0,0,0,0}, siO = {0,0,0,0};
#pragma unroll
    for (int j = 0; j < 16; ++j) {
      const float4 r1 = *(const float4*)&o1r[j*16 + kq*4];
      const float4 i1 = *(const float4*)&o1i[j*16 + kq*4];
      const float4 r2 = *(const float4*)&o2r[j*16 + kq*4];
      const float4 i2 = *(const float4*)&o2i[j*16 + kq*4];
      float4& sr = (j & 1) ? srO : srE;
      float4& si = (j & 1) ? siO : siE;
      sr.x += r1.x*c1 - i1.x*s1 + r2.x*cB - i2.x*sB;
      si.x += r1.x*s1 + i1.x*c1 + r2.x*sB + i2.x*cB;
      sr.y += r1.y*c1 - i1.y*s1 + r2.y*cB - i2.y*sB;
      si.y += r1.y*s1 + i1.y*c1 + r2.y*sB + i2.y*cB;
      sr.z += r1.z*c1 - i1.z*s1 + r2.z*cB - i2.z*sB;
      si.z += r1.z*s1 + i1.z*c1 + r2.z*sB + i2.z*cB;
      sr.w += r1.w*c1 - i1.w*s1 + r2.w*cB - i2.w*sB;
      si.w += r1.w*s1 + i1.w*c1 + r2.w*sB + i2.w*cB;
      const float n1c = c1*chh - s1*shh, n1s = s1*chh + c1*shh;
      const float n2c = cB*chh - sB*shh, n2s = sB*chh + cB*shh;
      c1 = n1c; s1 = n1s; cB = n2c; sB = n2s;
    }
    float4 sp, sm;
    sp.x = srE.x + srO.x; sp.y = srE.y + srO.y; sp.z = srE.z + srO.z; sp.w = srE.w + srO.w;
    sm.x = srE.x - srO.x; sm.y = srE.y - srO.y; sm.z = srE.z - srO.z; sm.w = srE.w - srO.w;
    *(float4*)&Sr[h][kq*4]       = sp;
    *(float4*)&Sr[h+128][kq*4]   = sm;
    sp.x = siE.x + siO.x; sp.y = siE.y + siO.y; sp.z = siE.z + siO.z; sp.w = siE.w + siO.w;
    sm.x = siE.x - siO.x; sm.y = siE.y - siO.y; sm.z = siE.z - siO.z; sm.w = siE.w - siO.w;
    *(float4*)&Si[h][kq*4]       = sp;
    *(float4*)&Si[h+128][kq*4]   = sm;
  }
  __syncthreads();

  // ---- phase B trig ----
  const int wl = t & 31;
  float c[15], s[15], c2[15], s2[15];
#pragma unroll
  for (int k = 0; k < 15; ++k) {
    const int mi = ((k+1) * wl) & 255;
    c[k] = cst[mi];
    s[k] = snt[mi];
  }
  {
    const float R = 0.70710678118654752f;
#pragma unroll
    for (int k = 0; k < 15; ++k) {
      const int r8 = (k + 1) & 7;
      switch (r8) {
        case 0: c2[k] =  c[k];            s2[k] =  s[k];            break;
        case 1: c2[k] = (c[k]-s[k])*R;    s2[k] = (s[k]+c[k])*R;    break;
        case 2: c2[k] = -s[k];            s2[k] =  c[k];            break;
        case 3: c2[k] = -(c[k]+s[k])*R;   s2[k] = (c[k]-s[k])*R;    break;
        case 4: c2[k] = -c[k];            s2[k] = -s[k];            break;
        case 5: c2[k] = (s[k]-c[k])*R;    s2[k] = -(c[k]+s[k])*R;   break;
        case 6: c2[k] =  s[k];            s2[k] = -c[k];            break;
        default:c2[k] = (c[k]+s[k])*R;    s2[k] = (s[k]-c[k])*R;    break;
      }
    }
  }

  // ---- phase B: 256 rows, 8 waves x 32 rows, row-paired radix-4 ----
  const int half = (t >> 5) & 1;
  const int wv = t >> 6;               // 0..7
  const float scale = 2.0f / 65536.0f;
  const size_t base256 = (size_t)bo * 256;
#pragma unroll 2
  for (int pr = 0; pr < 16; ++pr) {
    const int lr = wv*32 + pr*2 + half;      // row 0..255 (= global h)
    const float4 a0 = *(const float4*)&Sr[lr][0];
    const float4 a1 = *(const float4*)&Sr[lr][4];
    const float4 a2 = *(const float4*)&Sr[lr][8];
    const float4 a3 = *(const float4*)&Sr[lr][12];
    const float4 b0 = *(const float4*)&Si[lr][0];
    const float4 b1 = *(const float4*)&Si[lr][4];
    const float4 b2 = *(const float4*)&Si[lr][8];
    const float4 b3 = *(const float4*)&Si[lr][12];
    const float re[16] = {a0.x,a0.y,a0.z,a0.w, a1.x,a1.y,a1.z,a1.w,
                          a2.x,a2.y,a2.z,a2.w, a3.x,a3.y,a3.z,a3.w};
    const float im[16] = {b0.x,b0.y,b0.z,b0.w, b1.x,b1.y,b1.z,b1.w,
                          b2.x,b2.y,b2.z,b2.w, b3.x,b3.y,b3.z,b3.w};
    const size_t ob = (base256 + lr) * 256;

#pragma unroll
    for (int g = 0; g < 2; ++g) {
      const float* cc = g ? c2 : c;
      const float* ss = g ? s2 : s;
      float PA = 0.5f * re[0];
      float PB = 0.f, PC = 0.f, PD = 0.f, QB = 0.f, QD = 0.f;
#pragma unroll
      for (int k = 0; k < 15; ++k) {
        const int ky = k + 1;
        const float R = re[ky], I = im[ky];
        const int cls = ky & 3;
        if (cls == 0)      PA += R*cc[k] - I*ss[k];
        else if (cls == 1) { PB += R*cc[k] - I*ss[k];  QB += R*ss[k] + I*cc[k]; }
        else if (cls == 2) PC += R*cc[k] - I*ss[k];
        else               { PD += R*cc[k] - I*ss[k];  QD += R*ss[k] + I*cc[k]; }
      }
      const float T1 = PA + PC, T2 = PB + PD;
      const float T3 = PA - PC, T4 = QB - QD;
      const int cb = wl + g*32;
      out[ob + cb]       = (T1 + T2) * scale;
      out[ob + cb + 64]  = (T3 - T4) * scale;
      out[ob + cb + 128] = (T1 - T2) * scale;
      out[ob + cb + 192] = (T3 + T4) * scale;
    }
  }
}

extern "C" void kernel_launch(void* const* d_in, const int* in_sizes, int n_in,
                              void* d_out, int out_size, void* d_ws, size_t ws_size,
                              hipStream_t stream) {
  const float* x   = (const float*)d_in[0];
  const float* w1r = (const float*)d_in[1];
  const float* w1i = (const float*)d_in[2];
  const float* w2r = (const float*)d_in[3];
  const float* w2i = (const float*)d_in[4];
  float* out = (float*)d_out;
  float* ws  = (float*)d_ws;

  hipLaunchKernelGGL(k12_dft,   dim3(256), dim3(1024), 0, stream, x, ws);
  hipLaunchKernelGGL(k345_idft, dim3(256), dim3(512),  0, stream,
                     w1r, w1i, w2r, w2i, ws, out);
}